// Round 5
// baseline (354.906 us; speedup 1.0000x reference)
//
#include <hip/hip_runtime.h>
#include <hip/hip_bf16.h>
#include <cstdint>
#include <cstddef>

#define BN_EPS 1e-5f

typedef short short8 __attribute__((ext_vector_type(8)));
typedef float float16 __attribute__((ext_vector_type(16)));
typedef unsigned short ushort_t;

__device__ __forceinline__ float bf2f(ushort_t u) {
  return __uint_as_float(((unsigned int)u) << 16);
}
__device__ __forceinline__ ushort_t f2bf(float f) {
  unsigned int u = __float_as_uint(f);
  u += 0x7FFFu + ((u >> 16) & 1u);
  return (ushort_t)(u >> 16);
}

// async global -> LDS, 16 B per lane; dest is wave-uniform base (+lane*16 in HW)
__device__ __forceinline__ void gload16(const ushort_t* g, ushort_t* l) {
  __builtin_amdgcn_global_load_lds(
      (const __attribute__((address_space(1))) unsigned int*)g,
      (__attribute__((address_space(3))) unsigned int*)l, 16, 0, 0);
}

// ------------------------------------------------------------------
// Weight prep: OIHW fp32 -> fragment-ordered bf16 (Kc=32, 18 K16 slices)
// ------------------------------------------------------------------

__device__ __forceinline__ void prep_one(const float* __restrict__ w,
                                         ushort_t* __restrict__ w2, int C, int N,
                                         int Ntg, int chunks, int u) {
  int total = chunks * 9 * 2 * Ntg * 64;
  if (u >= total) return;
  int l = u & 63;
  int g = u >> 6;
  int ntg = g % Ntg;
  int g2 = g / Ntg;
  int s = g2 & 1;
  int g3 = g2 >> 1;
  int pos = g3 % 9;
  int cc = g3 / 9;
  int n = ntg * 32 + (l & 31);
  int c0 = cc * 32 + s * 16 + (l >> 5) * 8;
  ushort_t o8[8];
#pragma unroll
  for (int j = 0; j < 8; ++j) {
    int c = c0 + j;
    float v = (n < N && c < C) ? w[((size_t)n * C + c) * 9 + pos] : 0.f;
    o8[j] = f2bf(v);
  }
  *(uint4*)&w2[(size_t)u * 8] = *(const uint4*)o8;
}

__device__ __forceinline__ void prep_head_one(const float* __restrict__ hb,
                                              const float* __restrict__ hc,
                                              ushort_t* __restrict__ w2, int u) {
  int total = 8 * 9 * 2 * 64;
  if (u >= total) return;
  int l = u & 63;
  int g = u >> 6;
  int s = g & 1;
  int g3 = g >> 1;
  int pos = g3 % 9;
  int cc = g3 / 9;
  int n = l & 31;
  int c0 = cc * 32 + s * 16 + (l >> 5) * 8;
  ushort_t o8[8];
#pragma unroll
  for (int j = 0; j < 8; ++j) {
    int c = c0 + j;
    float v = 0.f;
    if (n < 21) v = hb[((size_t)n * 256 + c) * 9 + pos];
    else if (n < 24) v = hc[((size_t)(n - 21) * 256 + c) * 9 + pos];
    o8[j] = f2bf(v);
  }
  *(uint4*)&w2[(size_t)u * 8] = *(const uint4*)o8;
}

// ------------------------------------------------------------------
// fused_prep: blocks [0,234) weight prep; [234,490) pillar moments.
// ------------------------------------------------------------------

__global__ __launch_bounds__(256) void fused_prep(
    const float* __restrict__ c1_w, const float* __restrict__ c2_w,
    const float* __restrict__ h1_w, const float* __restrict__ hb_w,
    const float* __restrict__ hc_w, ushort_t* __restrict__ w2c1,
    ushort_t* __restrict__ w2c2, ushort_t* __restrict__ w2h1,
    ushort_t* __restrict__ w2hd, const float* __restrict__ pillars,
    float* __restrict__ mom) {
  int b = blockIdx.x;
  int t = threadIdx.x;
  if (b < 18) { prep_one(c1_w, w2c1, 64, 64, 2, 2, b * 256 + t); return; }
  if (b < 54) { prep_one(c2_w, w2c2, 64, 128, 4, 2, (b - 18) * 256 + t); return; }
  if (b < 198) { prep_one(h1_w, w2h1, 128, 256, 8, 4, (b - 54) * 256 + t); return; }
  if (b < 234) { prep_head_one(hb_w, hc_w, w2hd, (b - 198) * 256 + t); return; }
  // ---- pillar moments: S[9], M[45] upper-tri, 256 blocks x 256 thr ----
  float S[9], M[45];
#pragma unroll
  for (int i = 0; i < 9; ++i) S[i] = 0.f;
#pragma unroll
  for (int i = 0; i < 45; ++i) M[i] = 0.f;
  const int t0 = (b - 234) * 256 + t;
  const int NTH = 256 * 256;
  for (long r = t0; r < 640000; r += NTH) {
    float x[9];
    const float* rp = pillars + r * 9;
#pragma unroll
    for (int d = 0; d < 9; ++d) x[d] = rp[d];
    int k = 0;
#pragma unroll
    for (int i = 0; i < 9; ++i) {
      S[i] += x[i];
#pragma unroll
      for (int j = i; j < 9; ++j) { M[k] += x[i] * x[j]; ++k; }
    }
  }
#pragma unroll
  for (int i = 0; i < 9; ++i)
#pragma unroll
    for (int o = 32; o > 0; o >>= 1) S[i] += __shfl_xor(S[i], o);
#pragma unroll
  for (int i = 0; i < 45; ++i)
#pragma unroll
    for (int o = 32; o > 0; o >>= 1) M[i] += __shfl_xor(M[i], o);
  __shared__ float red[4 * 54];
  int lane = t & 63, wv = t >> 6;
  if (lane == 0) {
#pragma unroll
    for (int i = 0; i < 9; ++i) red[wv * 54 + i] = S[i];
#pragma unroll
    for (int i = 0; i < 45; ++i) red[wv * 54 + 9 + i] = M[i];
  }
  __syncthreads();
  if (t < 54) {
    float s = 0.f;
#pragma unroll
    for (int w4 = 0; w4 < 4; ++w4) s += red[w4 * 54 + t];
    atomicAdd(&mom[t], s);
  }
}

// ------------------------------------------------------------------
// pfn_finalize: 64 threads; double-precision algebra moments -> scale/shift
// ------------------------------------------------------------------

__global__ void pfn_finalize(const float* __restrict__ mom,
                             const float* __restrict__ lin_w,
                             const float* __restrict__ lin_b,
                             const float* __restrict__ g, const float* __restrict__ b,
                             float* __restrict__ ss) {
  int c = threadIdx.x;
  double w[9], S[9];
#pragma unroll
  for (int d = 0; d < 9; ++d) {
    w[d] = (double)lin_w[c * 9 + d];
    S[d] = (double)mom[d];
  }
  double wS = 0.0;
#pragma unroll
  for (int d = 0; d < 9; ++d) wS += w[d] * S[d];
  double wMw = 0.0;
  int k = 0;
#pragma unroll
  for (int i = 0; i < 9; ++i)
#pragma unroll
    for (int j = i; j < 9; ++j) {
      double m = (double)mom[9 + k];
      wMw += (i == j ? 1.0 : 2.0) * w[i] * w[j] * m;
      ++k;
    }
  const double N = 640000.0;
  double bc = (double)lin_b[c];
  double mean = (wS + N * bc) / N;
  double ey2 = (wMw + 2.0 * bc * wS + N * bc * bc) / N;
  double var = ey2 - mean * mean;
  if (var < 0.0) var = 0.0;
  double inv = 1.0 / sqrt(var + (double)BN_EPS);
  double sc = (double)g[c] * inv;
  ss[c] = (float)sc;
  ss[c + 64] = (float)((double)b[c] - mean * sc);
}

// ------------------------------------------------------------------
// feats_scatter: blocks [0,5000) PFN feats; [5000,5079) winner scatter.
// ------------------------------------------------------------------

__global__ __launch_bounds__(256) void feats_scatter(
    const float* __restrict__ pillars, const float* __restrict__ lin_w,
    const float* __restrict__ lin_b, const float* __restrict__ ss,
    ushort_t* __restrict__ feats, const int* __restrict__ coords,
    int* __restrict__ winner) {
  int tid = threadIdx.x;
  if (blockIdx.x < 5000) {
    __shared__ float s_p[1152];
    int c = tid & 63, pe = tid >> 6;
    long pb = (long)blockIdx.x * 4;
    for (int i = tid; i < 1152; i += 256) s_p[i] = pillars[pb * 288 + i];
    float w[9];
#pragma unroll
    for (int d = 0; d < 9; ++d) w[d] = lin_w[c * 9 + d];
    float bl = lin_b[c];
    float sc = ss[c], sh = ss[c + 64];
    __syncthreads();
    const float* pp = &s_p[pe * 288];
    float m = -1e30f;
#pragma unroll 4
    for (int n = 0; n < 32; ++n) {
      float y = bl;
#pragma unroll
      for (int d = 0; d < 9; ++d) y += pp[n * 9 + d] * w[d];
      float v = fmaxf(y * sc + sh, 0.f);
      m = fmaxf(m, v);
    }
    feats[(pb + pe) * 64 + c] = f2bf(m);
  } else {
    int p = (blockIdx.x - 5000) * 256 + tid;
    if (p >= 20000) return;
    int y = coords[p * 3 + 1], x = coords[p * 3 + 2];
    if (y >= 0 && y < 666 && x >= 0 && x < 666) atomicMax(&winner[y * 666 + x], p);
  }
}

// ------------------------------------------------------------------
// conv_g: conv1 only. Async gather conv (R3-proven): winner->feats
// indirection, all staging via global_load_lds, K=16 phases double-
// buffered (stage(ph+1) issued after barrier, drained next barrier).
// Fused BN stats + raw 2x2 max-pool.
// ------------------------------------------------------------------

template <int NT, int WAVES>
__global__ __launch_bounds__(WAVES * 64, 4) void conv_g(
    const int* __restrict__ winner, const ushort_t* __restrict__ feats,
    const ushort_t* __restrict__ w2, const float* __restrict__ bias,
    const ushort_t* __restrict__ zbuf, ushort_t* __restrict__ obf,
    float* __restrict__ statacc, int W, int H, int nchunks, int Ntg) {
  constexpr int NTHREADS = WAVES * 64;
  constexpr int NPOS = (WAVES + 2) * 66;
  constexpr int IN_U4 = NPOS * 2;
  constexpr int W_U4 = 9 * NT * 64;
  constexpr int INIT = (IN_U4 + NTHREADS - 1) / NTHREADS;
  constexpr int WIT = (W_U4 + NTHREADS - 1) / NTHREADS;
  constexpr int IN_SLOTS = ((IN_U4 + 63) / 64) * 64;
  __shared__ ushort_t s_in[2][IN_SLOTS * 8];
  __shared__ ushort_t s_w[2][W_U4 * 8];
  __shared__ ushort_t s_junk[512];
  const int tid = threadIdx.x;
  const int lane = tid & 63, wv = tid >> 6;
  const int lc = lane & 31, lh = lane >> 5;
  const int x0 = blockIdx.x * 64, y0 = blockIdx.y * WAVES;
  const int z = blockIdx.z;
  const int z_oc = z;

  int pc[2][3];
#pragma unroll
  for (int Mt = 0; Mt < 2; ++Mt)
#pragma unroll
    for (int kx = 0; kx < 3; ++kx) {
      int col = Mt * 32 + kx + lc;
      pc[Mt][kx] = col * 16 + (lh ^ (col & 1)) * 8;
    }

  const ushort_t* isrc[INIT];
#pragma unroll
  for (int it = 0; it < INIT; ++it) {
    isrc[it] = zbuf;
    int d = it * NTHREADS + tid;
    if (d < IN_U4) {
      int p = d >> 1, g = d & 1;
      int r = p / 66, col = p - r * 66;
      int cg = g ^ (col & 1);
      int gy = y0 - 1 + r, gx = x0 - 1 + col;
      if (gy >= 0 && gy < H && gx >= 0 && gx < W) {
        int pw = winner[gy * 666 + gx];
        if (pw >= 0) isrc[it] = feats + pw * 64 + cg * 8;
      }
    }
  }
  int wof[WIT];
#pragma unroll
  for (int it = 0; it < WIT; ++it) {
    wof[it] = 0;
    int d = it * NTHREADS + tid;
    if (d < W_U4) {
      int grp = d >> 6, l16 = d & 63;
      int pos = grp / NT, nt = grp % NT;
      wof[it] = (pos * 2 * Ntg + z_oc * NT + nt) * 512 + l16 * 8;
    }
  }

  float bv[NT];
#pragma unroll
  for (int nt = 0; nt < NT; ++nt) bv[nt] = bias[(z * NT + nt) * 32 + lc];
  float16 acc[2][NT];
#pragma unroll
  for (int Mt = 0; Mt < 2; ++Mt)
#pragma unroll
    for (int nt = 0; nt < NT; ++nt)
#pragma unroll
      for (int r = 0; r < 16; ++r) acc[Mt][nt][r] = bv[nt];

  auto stage = [&](int ph, int b) {
    int ccg = ph >> 1, sh2 = ph & 1;
    int coff = ccg * 32 + sh2 * 16;
#pragma unroll
    for (int it = 0; it < INIT; ++it) {
      int d = it * NTHREADS + tid;
      if (d < IN_U4)
        gload16(isrc[it] + coff, &s_in[b][(size_t)(it * NTHREADS + wv * 64) * 8]);
    }
    int wbase = (ccg * 18 + sh2) * Ntg * 512;
#pragma unroll
    for (int it = 0; it < WIT; ++it) {
      int d = it * NTHREADS + tid;
      if (d < W_U4)
        gload16(w2 + wbase + wof[it], &s_w[b][(size_t)(it * NTHREADS + wv * 64) * 8]);
    }
  };

  auto compute_phase = [&](int b) {
#pragma unroll
    for (int ky = 0; ky < 3; ++ky) {
      const ushort_t* rowp = &s_in[b][(wv + ky) * (66 * 16)];
#pragma unroll
      for (int kx = 0; kx < 3; ++kx) {
        const int pos = ky * 3 + kx;
        short8 Bf[NT];
#pragma unroll
        for (int nt = 0; nt < NT; ++nt)
          Bf[nt] = *(const short8*)&s_w[b][(pos * NT + nt) * 512 + lane * 8];
#pragma unroll
        for (int Mt = 0; Mt < 2; ++Mt) {
          short8 Af = *(const short8*)&rowp[pc[Mt][kx]];
#pragma unroll
          for (int nt = 0; nt < NT; ++nt)
            acc[Mt][nt] =
                __builtin_amdgcn_mfma_f32_32x32x16_bf16(Af, Bf[nt], acc[Mt][nt], 0, 0, 0);
        }
      }
    }
  };

  const int nph = nchunks * 2;
  stage(0, 0);
  for (int ph = 0; ph < nph; ++ph) {
    asm volatile("s_waitcnt vmcnt(0)\n\ts_barrier" ::: "memory");
    if (ph + 1 < nph) stage(ph + 1, (ph + 1) & 1);
    __builtin_amdgcn_s_setprio(1);
    compute_phase(ph & 1);
    __builtin_amdgcn_s_setprio(0);
  }

  // ---- epilogue: fused BN stats + 2x2 max-pool store ----
  const int y = y0 + wv;
  const bool yok = (y < H);
  const int Ntot = Ntg * 32;

  {
    float s1[NT], s2[NT];
#pragma unroll
    for (int nt = 0; nt < NT; ++nt) { s1[nt] = 0.f; s2[nt] = 0.f; }
    if (yok) {
#pragma unroll
      for (int Mt = 0; Mt < 2; ++Mt)
#pragma unroll
        for (int r = 0; r < 16; ++r) {
          int m = (r & 3) + 8 * (r >> 2) + 4 * lh;
          int x = x0 + Mt * 32 + m;
          if (x < W) {
#pragma unroll
            for (int nt = 0; nt < NT; ++nt) {
              float v = acc[Mt][nt][r];
              s1[nt] += v;
              s2[nt] += v * v;
            }
          }
        }
    }
#pragma unroll
    for (int nt = 0; nt < NT; ++nt) {
      s1[nt] += __shfl_xor(s1[nt], 32);
      s2[nt] += __shfl_xor(s2[nt], 32);
    }
    __syncthreads();
    float* red = (float*)s_in;
    if (lh == 0) {
#pragma unroll
      for (int nt = 0; nt < NT; ++nt) {
        red[(wv * NT + nt) * 32 + lc] = s1[nt];
        red[WAVES * NT * 32 + (wv * NT + nt) * 32 + lc] = s2[nt];
      }
    }
    __syncthreads();
    if (wv == 0 && lh == 0) {
#pragma unroll
      for (int nt = 0; nt < NT; ++nt) {
        float a = 0.f, b = 0.f;
#pragma unroll
        for (int w8 = 0; w8 < WAVES; ++w8) {
          a += red[(w8 * NT + nt) * 32 + lc];
          b += red[WAVES * NT * 32 + (w8 * NT + nt) * 32 + lc];
        }
        int ch = (z * NT + nt) * 32 + lc;
        atomicAdd(&statacc[ch], a);
        atomicAdd(&statacc[ch + 256], b);
      }
    }
  }

  {
    const int OWp = W >> 1, OHp = H >> 1;
    float hm[2][NT][8];
#pragma unroll
    for (int Mt = 0; Mt < 2; ++Mt)
#pragma unroll
      for (int nt = 0; nt < NT; ++nt)
#pragma unroll
        for (int i = 0; i < 8; ++i)
          hm[Mt][nt][i] = fmaxf(acc[Mt][nt][2 * i], acc[Mt][nt][2 * i + 1]);
    __syncthreads();
    float* pl = (float*)s_in;
    if (wv & 1) {
#pragma unroll
      for (int Mt = 0; Mt < 2; ++Mt)
#pragma unroll
        for (int nt = 0; nt < NT; ++nt)
#pragma unroll
          for (int i = 0; i < 8; ++i)
            pl[((((wv >> 1) * 2 + Mt) * NT + nt) * 8 + i) * 64 + lane] = hm[Mt][nt][i];
    }
    __syncthreads();
    if (!(wv & 1)) {
      int oy = (y0 + wv) >> 1;
      if (oy < OHp) {
#pragma unroll
        for (int Mt = 0; Mt < 2; ++Mt)
#pragma unroll
          for (int i = 0; i < 8; ++i) {
            int pxl = Mt * 16 + (i >> 1) * 4 + (i & 1) + 2 * lh;
            int ox = (x0 >> 1) + pxl;
            if (ox < OWp) {
#pragma unroll
              for (int nt = 0; nt < NT; ++nt) {
                float v = fmaxf(
                    hm[Mt][nt][i],
                    pl[((((wv >> 1) * 2 + Mt) * NT + nt) * 8 + i) * 64 + lane]);
                int oc = (z * NT + nt) * 32 + lc;
                obf[((size_t)oy * OWp + ox) * Ntot + oc] = f2bf(v);
              }
            }
          }
      }
    }
  }
}

// ------------------------------------------------------------------
// conv_s: sync MODE-1 conv (R0-proven): BN+relu fused at staging from
// raw bf16 HWC; BN coefs computed IN-BLOCK from stat accumulators
// (deletes bn_make_coefs launches). HEAD: K-split z, atomicAdd fp32
// directly into pre-zeroed CHW output (deletes head_reduce + hpart).
// STATS: fused BN stats. POOL: fused raw 2x2 max-pool.
// ------------------------------------------------------------------

template <int NT, int WAVES, bool HEAD, bool STATS, bool POOL>
__global__ __launch_bounds__(WAVES * 64, WAVES == 8 ? 4 : 3) void conv_s(
    const ushort_t* __restrict__ in, const ushort_t* __restrict__ w2,
    const float* __restrict__ bias, const float* __restrict__ bias2,
    const float* __restrict__ bnacc, const float* __restrict__ bng,
    const float* __restrict__ bnb, float invN, ushort_t* __restrict__ obf,
    float* __restrict__ hout, float* __restrict__ statacc, int W, int H, int C,
    int nchunks, int Ntg) {
  constexpr int NTHREADS = WAVES * 64;
  __shared__ ushort_t s_in[(WAVES + 2) * 66 * 32];
  __shared__ ushort_t s_w[9 * 2 * NT * 512];
  __shared__ float s_coef[512];
  const int tid = threadIdx.x;
  const int lane = tid & 63, wv = tid >> 6;
  const int lc = lane & 31, lh = lane >> 5;
  const int x0 = blockIdx.x * 64, y0 = blockIdx.y * WAVES;
  const int z = blockIdx.z;
  const int cc0 = HEAD ? z * nchunks : 0;
  const int z_oc = HEAD ? 0 : z;

  // in-block BN coef compute (covered by first loop-top __syncthreads)
  if (tid < C) {
    float m = bnacc[tid] * invN;
    float v = fmaxf(bnacc[tid + 256] * invN - m * m, 0.f);
    float sc = bng[tid] * rsqrtf(v + BN_EPS);
    s_coef[tid] = sc;
    s_coef[C + tid] = bnb[tid] - m * sc;
  }

  // per-lane A-address precompute
  int pc[2][2][3];
#pragma unroll
  for (int s = 0; s < 2; ++s)
#pragma unroll
    for (int Mt = 0; Mt < 2; ++Mt)
#pragma unroll
      for (int kx = 0; kx < 3; ++kx) {
        int col = Mt * 32 + kx + lc;
        int q = (2 * s + lh) ^ ((col >> 1) & 3);
        pc[s][Mt][kx] = col * 32 + q * 8;
      }

  // hoisted staging descriptors
  const int sg = tid & 3;
  const int tpos = tid >> 2;
  constexpr int TPOS = NTHREADS / 4;
  constexpr int NPOS = (WAVES + 2) * 66;
  constexpr int NIT = (NPOS + TPOS - 1) / TPOS;
  int ldst[NIT], gsrc[NIT];
#pragma unroll
  for (int it = 0; it < NIT; ++it) {
    ldst[it] = -1;
    gsrc[it] = -1;
    int p = tpos + it * TPOS;
    if (p < NPOS) {
      int r = p / 66, col = p - r * 66;
      int f = sg ^ ((col >> 1) & 3);
      ldst[it] = (r * 66 + col) * 32 + f * 8;
      int gy = y0 - 1 + r, gx = x0 - 1 + col;
      if (gy >= 0 && gy < H && gx >= 0 && gx < W)
        gsrc[it] = (gy * W + gx) * C + sg * 8;
    }
  }

  float bv[NT];
#pragma unroll
  for (int nt = 0; nt < NT; ++nt) {
    if (HEAD) {
      bv[nt] = (z == 0) ? (lc < 21 ? bias[lc] : (lc < 24 ? bias2[lc - 21] : 0.f)) : 0.f;
    } else {
      bv[nt] = bias[(z * NT + nt) * 32 + lc];
    }
  }
  float16 acc[2][NT];
#pragma unroll
  for (int Mt = 0; Mt < 2; ++Mt)
#pragma unroll
    for (int nt = 0; nt < NT; ++nt)
#pragma unroll
      for (int r = 0; r < 16; ++r) acc[Mt][nt][r] = bv[nt];

  for (int cc = 0; cc < nchunks; ++cc) {
    const int ccg = cc0 + cc;
    __syncthreads();
    // ---- stage input with fused BN+relu ----
    {
      float sc8[8], sh8[8];
      int ch = ccg * 32 + sg * 8;
      float4 a0 = *(const float4*)&s_coef[ch];
      float4 a1 = *(const float4*)&s_coef[ch + 4];
      float4 b0 = *(const float4*)&s_coef[C + ch];
      float4 b1 = *(const float4*)&s_coef[C + ch + 4];
      sc8[0] = a0.x; sc8[1] = a0.y; sc8[2] = a0.z; sc8[3] = a0.w;
      sc8[4] = a1.x; sc8[5] = a1.y; sc8[6] = a1.z; sc8[7] = a1.w;
      sh8[0] = b0.x; sh8[1] = b0.y; sh8[2] = b0.z; sh8[3] = b0.w;
      sh8[4] = b1.x; sh8[5] = b1.y; sh8[6] = b1.z; sh8[7] = b1.w;
#pragma unroll
      for (int it = 0; it < NIT; ++it) {
        if (ldst[it] < 0) continue;
        ushort_t v8[8] = {0, 0, 0, 0, 0, 0, 0, 0};
        if (gsrc[it] >= 0) {
          uint4 raw = *(const uint4*)&in[gsrc[it] + ccg * 32];
          const ushort_t* rp = (const ushort_t*)&raw;
#pragma unroll
          for (int j = 0; j < 8; ++j)
            v8[j] = f2bf(fmaxf(bf2f(rp[j]) * sc8[j] + sh8[j], 0.f));
        }
        *(uint4*)&s_in[ldst[it]] = *(const uint4*)v8;
      }
    }
    // ---- stage weight slice ----
    {
      const int NW = NT * 1152;
      for (int u = tid; u < NW; u += NTHREADS) {
        int l16 = u & 63, grp = u >> 6;
        int nt = grp % NT, ps = grp / NT;
        const ushort_t* src =
            w2 + ((size_t)((ccg * 18 + ps) * Ntg + z_oc * NT + nt) * 64 + l16) * 8;
        *(uint4*)&s_w[(size_t)u * 8] = *(const uint4*)src;
      }
    }
    __syncthreads();
#pragma unroll
    for (int ky = 0; ky < 3; ++ky) {
      int rowoff = (wv + ky) * (66 * 32);
#pragma unroll
      for (int kx = 0; kx < 3; ++kx) {
        const int pos = ky * 3 + kx;
#pragma unroll
        for (int s = 0; s < 2; ++s) {
          short8 Bf[NT];
#pragma unroll
          for (int nt = 0; nt < NT; ++nt)
            Bf[nt] = *(const short8*)&s_w[((pos * 2 + s) * NT + nt) * 512 + lane * 8];
#pragma unroll
          for (int Mt = 0; Mt < 2; ++Mt) {
            short8 Af = *(const short8*)&s_in[rowoff + pc[s][Mt][kx]];
#pragma unroll
            for (int nt = 0; nt < NT; ++nt)
              acc[Mt][nt] =
                  __builtin_amdgcn_mfma_f32_32x32x16_bf16(Af, Bf[nt], acc[Mt][nt], 0, 0, 0);
          }
        }
      }
    }
  }

  // ---- epilogue ----
  const int y = y0 + wv;
  const bool yok = (y < H);
  const int Ntot = Ntg * 32;

  if (HEAD) {
    if (yok && lc < 24) {
      float* op = hout + (size_t)lc * (size_t)(H * W);
#pragma unroll
      for (int Mt = 0; Mt < 2; ++Mt)
#pragma unroll
        for (int r = 0; r < 16; ++r) {
          int m = (r & 3) + 8 * (r >> 2) + 4 * lh;
          int x = x0 + Mt * 32 + m;
          if (x < W) atomicAdd(&op[(size_t)y * W + x], acc[Mt][0][r]);
        }
    }
    return;
  }

  if (!POOL) {
    if (yok) {
#pragma unroll
      for (int Mt = 0; Mt < 2; ++Mt)
#pragma unroll
        for (int r = 0; r < 16; ++r) {
          int m = (r & 3) + 8 * (r >> 2) + 4 * lh;
          int x = x0 + Mt * 32 + m;
          if (x < W) {
            size_t sp = (size_t)y * W + x;
#pragma unroll
            for (int nt = 0; nt < NT; ++nt) {
              int oc = (z * NT + nt) * 32 + lc;
              obf[sp * Ntot + oc] = f2bf(acc[Mt][nt][r]);
            }
          }
        }
    }
  }

  if (STATS) {
    float s1[NT], s2[NT];
#pragma unroll
    for (int nt = 0; nt < NT; ++nt) { s1[nt] = 0.f; s2[nt] = 0.f; }
    if (yok) {
#pragma unroll
      for (int Mt = 0; Mt < 2; ++Mt)
#pragma unroll
        for (int r = 0; r < 16; ++r) {
          int m = (r & 3) + 8 * (r >> 2) + 4 * lh;
          int x = x0 + Mt * 32 + m;
          if (x < W) {
#pragma unroll
            for (int nt = 0; nt < NT; ++nt) {
              float v = acc[Mt][nt][r];
              s1[nt] += v;
              s2[nt] += v * v;
            }
          }
        }
    }
#pragma unroll
    for (int nt = 0; nt < NT; ++nt) {
      s1[nt] += __shfl_xor(s1[nt], 32);
      s2[nt] += __shfl_xor(s2[nt], 32);
    }
    __syncthreads();
    float* red = (float*)s_in;
    if (lh == 0) {
#pragma unroll
      for (int nt = 0; nt < NT; ++nt) {
        red[(wv * NT + nt) * 32 + lc] = s1[nt];
        red[WAVES * NT * 32 + (wv * NT + nt) * 32 + lc] = s2[nt];
      }
    }
    __syncthreads();
    if (wv == 0 && lh == 0) {
#pragma unroll
      for (int nt = 0; nt < NT; ++nt) {
        float a = 0.f, b = 0.f;
#pragma unroll
        for (int w8 = 0; w8 < WAVES; ++w8) {
          a += red[(w8 * NT + nt) * 32 + lc];
          b += red[WAVES * NT * 32 + (w8 * NT + nt) * 32 + lc];
        }
        int ch = (z * NT + nt) * 32 + lc;
        atomicAdd(&statacc[ch], a);
        atomicAdd(&statacc[ch + 256], b);
      }
    }
  }

  if (POOL) {
    const int OWp = W >> 1, OHp = H >> 1;
    float hm[2][NT][8];
#pragma unroll
    for (int Mt = 0; Mt < 2; ++Mt)
#pragma unroll
      for (int nt = 0; nt < NT; ++nt)
#pragma unroll
        for (int i = 0; i < 8; ++i)
          hm[Mt][nt][i] = fmaxf(acc[Mt][nt][2 * i], acc[Mt][nt][2 * i + 1]);
    __syncthreads();
    float* pl = (float*)s_in;
    if (wv & 1) {
#pragma unroll
      for (int Mt = 0; Mt < 2; ++Mt)
#pragma unroll
        for (int nt = 0; nt < NT; ++nt)
#pragma unroll
          for (int i = 0; i < 8; ++i)
            pl[((((wv >> 1) * 2 + Mt) * NT + nt) * 8 + i) * 64 + lane] = hm[Mt][nt][i];
    }
    __syncthreads();
    if (!(wv & 1)) {
      int oy = (y0 + wv) >> 1;
      if (oy < OHp) {
#pragma unroll
        for (int Mt = 0; Mt < 2; ++Mt)
#pragma unroll
          for (int i = 0; i < 8; ++i) {
            int pxl = Mt * 16 + (i >> 1) * 4 + (i & 1) + 2 * lh;
            int ox = (x0 >> 1) + pxl;
            if (ox < OWp) {
#pragma unroll
              for (int nt = 0; nt < NT; ++nt) {
                float v = fmaxf(
                    hm[Mt][nt][i],
                    pl[((((wv >> 1) * 2 + Mt) * NT + nt) * 8 + i) * 64 + lane]);
                int oc = (z * NT + nt) * 32 + lc;
                obf[((size_t)oy * OWp + ox) * Ntot + oc] = f2bf(v);
              }
            }
          }
      }
    }
  }
}

// ------------------------------------------------------------------

extern "C" void kernel_launch(void* const* d_in, const int* in_sizes, int n_in,
                              void* d_out, int out_size, void* d_ws, size_t ws_size,
                              hipStream_t stream) {
  (void)in_sizes; (void)n_in; (void)out_size; (void)ws_size;
  const float* pillars = (const float*)d_in[0];
  const int* coords = (const int*)d_in[1];
  const float* lin_w = (const float*)d_in[2];
  const float* lin_b = (const float*)d_in[3];
  const float* pfn_g = (const float*)d_in[4];
  const float* pfn_b = (const float*)d_in[5];
  const float* c1_w = (const float*)d_in[6];
  const float* c1_b = (const float*)d_in[7];
  const float* bn1_g = (const float*)d_in[8];
  const float* bn1_b = (const float*)d_in[9];
  const float* c2_w = (const float*)d_in[10];
  const float* c2_b = (const float*)d_in[11];
  const float* bn2_g = (const float*)d_in[12];
  const float* bn2_b = (const float*)d_in[13];
  const float* h1_w = (const float*)d_in[14];
  const float* h1_b = (const float*)d_in[15];
  const float* hbn_g = (const float*)d_in[16];
  const float* hbn_b = (const float*)d_in[17];
  const float* hb_w = (const float*)d_in[18];
  const float* hb_b = (const float*)d_in[19];
  const float* hc_w = (const float*)d_in[20];
  const float* hc_b = (const float*)d_in[21];
  float* out = (float*)d_out;

  // ---- workspace layout (bytes) ----
  char* ws = (char*)d_ws;
  float* mom     = (float*)(ws + 0);          // 216 B
  float* pfn_ss  = (float*)(ws + 512);        // 512 B
  float* bn_acc1 = (float*)(ws + 1024);       // 2048 B
  float* bn_acc2 = (float*)(ws + 3072);       // 2048 B
  float* bn_acc3 = (float*)(ws + 5120);       // 2048 B
  ushort_t* zbuf = (ushort_t*)(ws + 10752);   // 512 B zeroed scratch page
  int* winner    = (int*)(ws + 11264);        // 1774224 B
  ushort_t* feats  = (ushort_t*)(ws + 1785600);    // 20000x64 bf16 = 2560000 B
  ushort_t* c1p    = (ushort_t*)(ws + 4345600);    // 333x333x64  raw pooled
  ushort_t* c2p    = (ushort_t*)(ws + 18539392);   // 166x166x128 raw pooled
  ushort_t* h1out  = (ushort_t*)(ws + 25593728);   // 166x166x256 raw
  ushort_t* w2c1   = (ushort_t*)(ws + 39702400);   // 73728 B
  ushort_t* w2c2   = (ushort_t*)(ws + 39776128);   // 147456 B
  ushort_t* w2h1   = (ushort_t*)(ws + 39923584);   // 589824 B
  ushort_t* w2hd   = (ushort_t*)(ws + 40513408);   // 147456 B

  // ---- upfront zero-init ----
  hipMemsetAsync(ws, 0, 11264, stream);                 // mom..zbuf (+ bn accs)
  hipMemsetAsync(winner, 0xFF, 1774224, stream);
  hipMemsetAsync(out, 0, 24 * 27556 * 4, stream);       // heads atomic target

  // ---- fused weight prep + pillar moments ----
  fused_prep<<<490, 256, 0, stream>>>(c1_w, c2_w, h1_w, hb_w, hc_w, w2c1, w2c2,
                                      w2h1, w2hd, pillars, mom);
  pfn_finalize<<<1, 64, 0, stream>>>(mom, lin_w, lin_b, pfn_g, pfn_b, pfn_ss);

  // ---- fused PFN feats + winner scatter ----
  feats_scatter<<<5079, 256, 0, stream>>>(pillars, lin_w, lin_b, pfn_ss, feats,
                                          coords, winner);

  // ---- conv1: async gather pipeline (R3-proven), stats+pool -> c1p ----
  conv_g<2, 8><<<dim3(11, 84, 1), 512, 0, stream>>>(
      winner, feats, w2c1, c1_b, zbuf, c1p, bn_acc1, 666, 666, 2, 2);

  // ---- conv2: sync MODE1 (BN from bn_acc1 in-block), stats+pool -> c2p ----
  conv_s<2, 8, false, true, true><<<dim3(6, 42, 2), 512, 0, stream>>>(
      c1p, w2c2, c2_b, nullptr, bn_acc1, bn1_g, bn1_b, 1.f / 443556.f, c2p, nullptr,
      bn_acc2, 333, 333, 64, 2, 4);

  // ---- h1: sync MODE1 (BN from bn_acc2), oc-split z=4, stats -> h1out ----
  conv_s<2, 4, false, true, false><<<dim3(3, 42, 4), 256, 0, stream>>>(
      c2p, w2h1, h1_b, nullptr, bn_acc2, bn2_g, bn2_b, 1.f / 110889.f, h1out, nullptr,
      bn_acc3, 166, 166, 128, 4, 8);

  // ---- heads: sync MODE1 (BN from bn_acc3), K-split z=4, atomic -> out ----
  conv_s<1, 4, true, false, false><<<dim3(3, 42, 4), 256, 0, stream>>>(
      h1out, w2hd, hb_b, hc_b, bn_acc3, hbn_g, hbn_b, 1.f / 27556.f, nullptr, out,
      nullptr, 166, 166, 256, 2, 1);
}

// Round 6
// 309.122 us; speedup vs baseline: 1.1481x; 1.1481x over previous
//
#include <hip/hip_runtime.h>
#include <hip/hip_bf16.h>
#include <cstdint>
#include <cstddef>

#define BN_EPS 1e-5f

typedef short short8 __attribute__((ext_vector_type(8)));
typedef float float16 __attribute__((ext_vector_type(16)));
typedef unsigned short ushort_t;

__device__ __forceinline__ float bf2f(ushort_t u) {
  return __uint_as_float(((unsigned int)u) << 16);
}
__device__ __forceinline__ ushort_t f2bf(float f) {
  unsigned int u = __float_as_uint(f);
  u += 0x7FFFu + ((u >> 16) & 1u);
  return (ushort_t)(u >> 16);
}

// async global -> LDS, 16 B per lane; dest is wave-uniform base (+lane*16 in HW)
__device__ __forceinline__ void gload16(const ushort_t* g, ushort_t* l) {
  __builtin_amdgcn_global_load_lds(
      (const __attribute__((address_space(1))) unsigned int*)g,
      (__attribute__((address_space(3))) unsigned int*)l, 16, 0, 0);
}

// ------------------------------------------------------------------
// Weight prep: OIHW fp32 -> fragment-ordered bf16 (Kc=32, 18 K16 slices)
// ------------------------------------------------------------------

__device__ __forceinline__ void prep_one(const float* __restrict__ w,
                                         ushort_t* __restrict__ w2, int C, int N,
                                         int Ntg, int chunks, int u) {
  int total = chunks * 9 * 2 * Ntg * 64;
  if (u >= total) return;
  int l = u & 63;
  int g = u >> 6;
  int ntg = g % Ntg;
  int g2 = g / Ntg;
  int s = g2 & 1;
  int g3 = g2 >> 1;
  int pos = g3 % 9;
  int cc = g3 / 9;
  int n = ntg * 32 + (l & 31);
  int c0 = cc * 32 + s * 16 + (l >> 5) * 8;
  ushort_t o8[8];
#pragma unroll
  for (int j = 0; j < 8; ++j) {
    int c = c0 + j;
    float v = (n < N && c < C) ? w[((size_t)n * C + c) * 9 + pos] : 0.f;
    o8[j] = f2bf(v);
  }
  *(uint4*)&w2[(size_t)u * 8] = *(const uint4*)o8;
}

__device__ __forceinline__ void prep_head_one(const float* __restrict__ hb,
                                              const float* __restrict__ hc,
                                              ushort_t* __restrict__ w2, int u) {
  int total = 8 * 9 * 2 * 64;
  if (u >= total) return;
  int l = u & 63;
  int g = u >> 6;
  int s = g & 1;
  int g3 = g >> 1;
  int pos = g3 % 9;
  int cc = g3 / 9;
  int n = l & 31;
  int c0 = cc * 32 + s * 16 + (l >> 5) * 8;
  ushort_t o8[8];
#pragma unroll
  for (int j = 0; j < 8; ++j) {
    int c = c0 + j;
    float v = 0.f;
    if (n < 21) v = hb[((size_t)n * 256 + c) * 9 + pos];
    else if (n < 24) v = hc[((size_t)(n - 21) * 256 + c) * 9 + pos];
    o8[j] = f2bf(v);
  }
  *(uint4*)&w2[(size_t)u * 8] = *(const uint4*)o8;
}

// ------------------------------------------------------------------
// fused_prep: blocks [0,234) weight prep; [234,490) pillar moments.
// ------------------------------------------------------------------

__global__ __launch_bounds__(256) void fused_prep(
    const float* __restrict__ c1_w, const float* __restrict__ c2_w,
    const float* __restrict__ h1_w, const float* __restrict__ hb_w,
    const float* __restrict__ hc_w, ushort_t* __restrict__ w2c1,
    ushort_t* __restrict__ w2c2, ushort_t* __restrict__ w2h1,
    ushort_t* __restrict__ w2hd, const float* __restrict__ pillars,
    float* __restrict__ mom) {
  int b = blockIdx.x;
  int t = threadIdx.x;
  if (b < 18) { prep_one(c1_w, w2c1, 64, 64, 2, 2, b * 256 + t); return; }
  if (b < 54) { prep_one(c2_w, w2c2, 64, 128, 4, 2, (b - 18) * 256 + t); return; }
  if (b < 198) { prep_one(h1_w, w2h1, 128, 256, 8, 4, (b - 54) * 256 + t); return; }
  if (b < 234) { prep_head_one(hb_w, hc_w, w2hd, (b - 198) * 256 + t); return; }
  // ---- pillar moments: S[9], M[45] upper-tri, 256 blocks x 256 thr ----
  float S[9], M[45];
#pragma unroll
  for (int i = 0; i < 9; ++i) S[i] = 0.f;
#pragma unroll
  for (int i = 0; i < 45; ++i) M[i] = 0.f;
  const int t0 = (b - 234) * 256 + t;
  const int NTH = 256 * 256;
  for (long r = t0; r < 640000; r += NTH) {
    float x[9];
    const float* rp = pillars + r * 9;
#pragma unroll
    for (int d = 0; d < 9; ++d) x[d] = rp[d];
    int k = 0;
#pragma unroll
    for (int i = 0; i < 9; ++i) {
      S[i] += x[i];
#pragma unroll
      for (int j = i; j < 9; ++j) { M[k] += x[i] * x[j]; ++k; }
    }
  }
#pragma unroll
  for (int i = 0; i < 9; ++i)
#pragma unroll
    for (int o = 32; o > 0; o >>= 1) S[i] += __shfl_xor(S[i], o);
#pragma unroll
  for (int i = 0; i < 45; ++i)
#pragma unroll
    for (int o = 32; o > 0; o >>= 1) M[i] += __shfl_xor(M[i], o);
  __shared__ float red[4 * 54];
  int lane = t & 63, wv = t >> 6;
  if (lane == 0) {
#pragma unroll
    for (int i = 0; i < 9; ++i) red[wv * 54 + i] = S[i];
#pragma unroll
    for (int i = 0; i < 45; ++i) red[wv * 54 + 9 + i] = M[i];
  }
  __syncthreads();
  if (t < 54) {
    float s = 0.f;
#pragma unroll
    for (int w4 = 0; w4 < 4; ++w4) s += red[w4 * 54 + t];
    atomicAdd(&mom[t], s);
  }
}

// ------------------------------------------------------------------
// pfn_finalize: 64 threads; double-precision algebra moments -> scale/shift
// ------------------------------------------------------------------

__global__ void pfn_finalize(const float* __restrict__ mom,
                             const float* __restrict__ lin_w,
                             const float* __restrict__ lin_b,
                             const float* __restrict__ g, const float* __restrict__ b,
                             float* __restrict__ ss) {
  int c = threadIdx.x;
  double w[9], S[9];
#pragma unroll
  for (int d = 0; d < 9; ++d) {
    w[d] = (double)lin_w[c * 9 + d];
    S[d] = (double)mom[d];
  }
  double wS = 0.0;
#pragma unroll
  for (int d = 0; d < 9; ++d) wS += w[d] * S[d];
  double wMw = 0.0;
  int k = 0;
#pragma unroll
  for (int i = 0; i < 9; ++i)
#pragma unroll
    for (int j = i; j < 9; ++j) {
      double m = (double)mom[9 + k];
      wMw += (i == j ? 1.0 : 2.0) * w[i] * w[j] * m;
      ++k;
    }
  const double N = 640000.0;
  double bc = (double)lin_b[c];
  double mean = (wS + N * bc) / N;
  double ey2 = (wMw + 2.0 * bc * wS + N * bc * bc) / N;
  double var = ey2 - mean * mean;
  if (var < 0.0) var = 0.0;
  double inv = 1.0 / sqrt(var + (double)BN_EPS);
  double sc = (double)g[c] * inv;
  ss[c] = (float)sc;
  ss[c + 64] = (float)((double)b[c] - mean * sc);
}

// ------------------------------------------------------------------
// feats_scatter: blocks [0,5000) PFN feats; [5000,5079) winner scatter.
// ------------------------------------------------------------------

__global__ __launch_bounds__(256) void feats_scatter(
    const float* __restrict__ pillars, const float* __restrict__ lin_w,
    const float* __restrict__ lin_b, const float* __restrict__ ss,
    ushort_t* __restrict__ feats, const int* __restrict__ coords,
    int* __restrict__ winner) {
  int tid = threadIdx.x;
  if (blockIdx.x < 5000) {
    __shared__ float s_p[1152];
    int c = tid & 63, pe = tid >> 6;
    long pb = (long)blockIdx.x * 4;
    for (int i = tid; i < 1152; i += 256) s_p[i] = pillars[pb * 288 + i];
    float w[9];
#pragma unroll
    for (int d = 0; d < 9; ++d) w[d] = lin_w[c * 9 + d];
    float bl = lin_b[c];
    float sc = ss[c], sh = ss[c + 64];
    __syncthreads();
    const float* pp = &s_p[pe * 288];
    float m = -1e30f;
#pragma unroll 4
    for (int n = 0; n < 32; ++n) {
      float y = bl;
#pragma unroll
      for (int d = 0; d < 9; ++d) y += pp[n * 9 + d] * w[d];
      float v = fmaxf(y * sc + sh, 0.f);
      m = fmaxf(m, v);
    }
    feats[(pb + pe) * 64 + c] = f2bf(m);
  } else {
    int p = (blockIdx.x - 5000) * 256 + tid;
    if (p >= 20000) return;
    int y = coords[p * 3 + 1], x = coords[p * 3 + 2];
    if (y >= 0 && y < 666 && x >= 0 && x < 666) atomicMax(&winner[y * 666 + x], p);
  }
}

// ------------------------------------------------------------------
// conv_g: conv1 only. Async gather conv (R3-proven): winner->feats
// indirection, all staging via global_load_lds, K=16 phases double-
// buffered. Fused BN stats + raw 2x2 max-pool.
// ------------------------------------------------------------------

template <int NT, int WAVES>
__global__ __launch_bounds__(WAVES * 64, 4) void conv_g(
    const int* __restrict__ winner, const ushort_t* __restrict__ feats,
    const ushort_t* __restrict__ w2, const float* __restrict__ bias,
    const ushort_t* __restrict__ zbuf, ushort_t* __restrict__ obf,
    float* __restrict__ statacc, int W, int H, int nchunks, int Ntg) {
  constexpr int NTHREADS = WAVES * 64;
  constexpr int NPOS = (WAVES + 2) * 66;
  constexpr int IN_U4 = NPOS * 2;
  constexpr int W_U4 = 9 * NT * 64;
  constexpr int INIT = (IN_U4 + NTHREADS - 1) / NTHREADS;
  constexpr int WIT = (W_U4 + NTHREADS - 1) / NTHREADS;
  constexpr int IN_SLOTS = ((IN_U4 + 63) / 64) * 64;
  __shared__ ushort_t s_in[2][IN_SLOTS * 8];
  __shared__ ushort_t s_w[2][W_U4 * 8];
  const int tid = threadIdx.x;
  const int lane = tid & 63, wv = tid >> 6;
  const int lc = lane & 31, lh = lane >> 5;
  const int x0 = blockIdx.x * 64, y0 = blockIdx.y * WAVES;
  const int z = blockIdx.z;
  const int z_oc = z;

  int pc[2][3];
#pragma unroll
  for (int Mt = 0; Mt < 2; ++Mt)
#pragma unroll
    for (int kx = 0; kx < 3; ++kx) {
      int col = Mt * 32 + kx + lc;
      pc[Mt][kx] = col * 16 + (lh ^ (col & 1)) * 8;
    }

  const ushort_t* isrc[INIT];
#pragma unroll
  for (int it = 0; it < INIT; ++it) {
    isrc[it] = zbuf;
    int d = it * NTHREADS + tid;
    if (d < IN_U4) {
      int p = d >> 1, g = d & 1;
      int r = p / 66, col = p - r * 66;
      int cg = g ^ (col & 1);
      int gy = y0 - 1 + r, gx = x0 - 1 + col;
      if (gy >= 0 && gy < H && gx >= 0 && gx < W) {
        int pw = winner[gy * 666 + gx];
        if (pw >= 0) isrc[it] = feats + pw * 64 + cg * 8;
      }
    }
  }
  int wof[WIT];
#pragma unroll
  for (int it = 0; it < WIT; ++it) {
    wof[it] = 0;
    int d = it * NTHREADS + tid;
    if (d < W_U4) {
      int grp = d >> 6, l16 = d & 63;
      int pos = grp / NT, nt = grp % NT;
      wof[it] = (pos * 2 * Ntg + z_oc * NT + nt) * 512 + l16 * 8;
    }
  }

  float bv[NT];
#pragma unroll
  for (int nt = 0; nt < NT; ++nt) bv[nt] = bias[(z * NT + nt) * 32 + lc];
  float16 acc[2][NT];
#pragma unroll
  for (int Mt = 0; Mt < 2; ++Mt)
#pragma unroll
    for (int nt = 0; nt < NT; ++nt)
#pragma unroll
      for (int r = 0; r < 16; ++r) acc[Mt][nt][r] = bv[nt];

  auto stage = [&](int ph, int b) {
    int ccg = ph >> 1, sh2 = ph & 1;
    int coff = ccg * 32 + sh2 * 16;
#pragma unroll
    for (int it = 0; it < INIT; ++it) {
      int d = it * NTHREADS + tid;
      if (d < IN_U4)
        gload16(isrc[it] + coff, &s_in[b][(size_t)(it * NTHREADS + wv * 64) * 8]);
    }
    int wbase = (ccg * 18 + sh2) * Ntg * 512;
#pragma unroll
    for (int it = 0; it < WIT; ++it) {
      int d = it * NTHREADS + tid;
      if (d < W_U4)
        gload16(w2 + wbase + wof[it], &s_w[b][(size_t)(it * NTHREADS + wv * 64) * 8]);
    }
  };

  auto compute_phase = [&](int b) {
#pragma unroll
    for (int ky = 0; ky < 3; ++ky) {
      const ushort_t* rowp = &s_in[b][(wv + ky) * (66 * 16)];
#pragma unroll
      for (int kx = 0; kx < 3; ++kx) {
        const int pos = ky * 3 + kx;
        short8 Bf[NT];
#pragma unroll
        for (int nt = 0; nt < NT; ++nt)
          Bf[nt] = *(const short8*)&s_w[b][(pos * NT + nt) * 512 + lane * 8];
#pragma unroll
        for (int Mt = 0; Mt < 2; ++Mt) {
          short8 Af = *(const short8*)&rowp[pc[Mt][kx]];
#pragma unroll
          for (int nt = 0; nt < NT; ++nt)
            acc[Mt][nt] =
                __builtin_amdgcn_mfma_f32_32x32x16_bf16(Af, Bf[nt], acc[Mt][nt], 0, 0, 0);
        }
      }
    }
  };

  const int nph = nchunks * 2;
  stage(0, 0);
  for (int ph = 0; ph < nph; ++ph) {
    asm volatile("s_waitcnt vmcnt(0)\n\ts_barrier" ::: "memory");
    if (ph + 1 < nph) stage(ph + 1, (ph + 1) & 1);
    __builtin_amdgcn_s_setprio(1);
    compute_phase(ph & 1);
    __builtin_amdgcn_s_setprio(0);
  }

  // ---- epilogue: fused BN stats + 2x2 max-pool store ----
  const int y = y0 + wv;
  const bool yok = (y < H);
  const int Ntot = Ntg * 32;

  {
    float s1[NT], s2[NT];
#pragma unroll
    for (int nt = 0; nt < NT; ++nt) { s1[nt] = 0.f; s2[nt] = 0.f; }
    if (yok) {
#pragma unroll
      for (int Mt = 0; Mt < 2; ++Mt)
#pragma unroll
        for (int r = 0; r < 16; ++r) {
          int m = (r & 3) + 8 * (r >> 2) + 4 * lh;
          int x = x0 + Mt * 32 + m;
          if (x < W) {
#pragma unroll
            for (int nt = 0; nt < NT; ++nt) {
              float v = acc[Mt][nt][r];
              s1[nt] += v;
              s2[nt] += v * v;
            }
          }
        }
    }
#pragma unroll
    for (int nt = 0; nt < NT; ++nt) {
      s1[nt] += __shfl_xor(s1[nt], 32);
      s2[nt] += __shfl_xor(s2[nt], 32);
    }
    __syncthreads();
    float* red = (float*)s_in;
    if (lh == 0) {
#pragma unroll
      for (int nt = 0; nt < NT; ++nt) {
        red[(wv * NT + nt) * 32 + lc] = s1[nt];
        red[WAVES * NT * 32 + (wv * NT + nt) * 32 + lc] = s2[nt];
      }
    }
    __syncthreads();
    if (wv == 0 && lh == 0) {
#pragma unroll
      for (int nt = 0; nt < NT; ++nt) {
        float a = 0.f, b = 0.f;
#pragma unroll
        for (int w8 = 0; w8 < WAVES; ++w8) {
          a += red[(w8 * NT + nt) * 32 + lc];
          b += red[WAVES * NT * 32 + (w8 * NT + nt) * 32 + lc];
        }
        int ch = (z * NT + nt) * 32 + lc;
        atomicAdd(&statacc[ch], a);
        atomicAdd(&statacc[ch + 256], b);
      }
    }
  }

  {
    const int OWp = W >> 1, OHp = H >> 1;
    float hm[2][NT][8];
#pragma unroll
    for (int Mt = 0; Mt < 2; ++Mt)
#pragma unroll
      for (int nt = 0; nt < NT; ++nt)
#pragma unroll
        for (int i = 0; i < 8; ++i)
          hm[Mt][nt][i] = fmaxf(acc[Mt][nt][2 * i], acc[Mt][nt][2 * i + 1]);
    __syncthreads();
    float* pl = (float*)s_in;
    if (wv & 1) {
#pragma unroll
      for (int Mt = 0; Mt < 2; ++Mt)
#pragma unroll
        for (int nt = 0; nt < NT; ++nt)
#pragma unroll
          for (int i = 0; i < 8; ++i)
            pl[((((wv >> 1) * 2 + Mt) * NT + nt) * 8 + i) * 64 + lane] = hm[Mt][nt][i];
    }
    __syncthreads();
    if (!(wv & 1)) {
      int oy = (y0 + wv) >> 1;
      if (oy < OHp) {
#pragma unroll
        for (int Mt = 0; Mt < 2; ++Mt)
#pragma unroll
          for (int i = 0; i < 8; ++i) {
            int pxl = Mt * 16 + (i >> 1) * 4 + (i & 1) + 2 * lh;
            int ox = (x0 >> 1) + pxl;
            if (ox < OWp) {
#pragma unroll
              for (int nt = 0; nt < NT; ++nt) {
                float v = fmaxf(
                    hm[Mt][nt][i],
                    pl[((((wv >> 1) * 2 + Mt) * NT + nt) * 8 + i) * 64 + lane]);
                int oc = (z * NT + nt) * 32 + lc;
                obf[((size_t)oy * OWp + ox) * Ntot + oc] = f2bf(v);
              }
            }
          }
      }
    }
  }
}

// ------------------------------------------------------------------
// conv_s: sync MODE-1 conv: BN+relu fused at staging from raw bf16 HWC;
// BN coefs computed IN-BLOCK from stat accumulators. HEAD: K-split z,
// coalesced fp32 partials into hpart (R0/R3-proven; atomics regressed
// 2.5x in R5 -- 64B-line RMW per CHW-scattered atomic).
// STATS: fused BN stats. POOL: fused raw 2x2 max-pool.
// ------------------------------------------------------------------

template <int NT, int WAVES, bool HEAD, bool STATS, bool POOL>
__global__ __launch_bounds__(WAVES * 64, WAVES == 8 ? 4 : 3) void conv_s(
    const ushort_t* __restrict__ in, const ushort_t* __restrict__ w2,
    const float* __restrict__ bias, const float* __restrict__ bias2,
    const float* __restrict__ bnacc, const float* __restrict__ bng,
    const float* __restrict__ bnb, float invN, ushort_t* __restrict__ obf,
    float* __restrict__ hpart, float* __restrict__ statacc, int W, int H, int C,
    int nchunks, int Ntg) {
  constexpr int NTHREADS = WAVES * 64;
  __shared__ ushort_t s_in[(WAVES + 2) * 66 * 32];
  __shared__ ushort_t s_w[9 * 2 * NT * 512];
  __shared__ float s_coef[512];
  const int tid = threadIdx.x;
  const int lane = tid & 63, wv = tid >> 6;
  const int lc = lane & 31, lh = lane >> 5;
  const int x0 = blockIdx.x * 64, y0 = blockIdx.y * WAVES;
  const int z = blockIdx.z;
  const int cc0 = HEAD ? z * nchunks : 0;
  const int z_oc = HEAD ? 0 : z;

  // in-block BN coef compute (covered by first loop-top __syncthreads)
  if (tid < C) {
    float m = bnacc[tid] * invN;
    float v = fmaxf(bnacc[tid + 256] * invN - m * m, 0.f);
    float sc = bng[tid] * rsqrtf(v + BN_EPS);
    s_coef[tid] = sc;
    s_coef[C + tid] = bnb[tid] - m * sc;
  }

  // per-lane A-address precompute
  int pc[2][2][3];
#pragma unroll
  for (int s = 0; s < 2; ++s)
#pragma unroll
    for (int Mt = 0; Mt < 2; ++Mt)
#pragma unroll
      for (int kx = 0; kx < 3; ++kx) {
        int col = Mt * 32 + kx + lc;
        int q = (2 * s + lh) ^ ((col >> 1) & 3);
        pc[s][Mt][kx] = col * 32 + q * 8;
      }

  // hoisted staging descriptors
  const int sg = tid & 3;
  const int tpos = tid >> 2;
  constexpr int TPOS = NTHREADS / 4;
  constexpr int NPOS = (WAVES + 2) * 66;
  constexpr int NIT = (NPOS + TPOS - 1) / TPOS;
  int ldst[NIT], gsrc[NIT];
#pragma unroll
  for (int it = 0; it < NIT; ++it) {
    ldst[it] = -1;
    gsrc[it] = -1;
    int p = tpos + it * TPOS;
    if (p < NPOS) {
      int r = p / 66, col = p - r * 66;
      int f = sg ^ ((col >> 1) & 3);
      ldst[it] = (r * 66 + col) * 32 + f * 8;
      int gy = y0 - 1 + r, gx = x0 - 1 + col;
      if (gy >= 0 && gy < H && gx >= 0 && gx < W)
        gsrc[it] = (gy * W + gx) * C + sg * 8;
    }
  }

  float bv[NT];
#pragma unroll
  for (int nt = 0; nt < NT; ++nt) {
    if (HEAD) {
      bv[nt] = (z == 0) ? (lc < 21 ? bias[lc] : (lc < 24 ? bias2[lc - 21] : 0.f)) : 0.f;
    } else {
      bv[nt] = bias[(z * NT + nt) * 32 + lc];
    }
  }
  float16 acc[2][NT];
#pragma unroll
  for (int Mt = 0; Mt < 2; ++Mt)
#pragma unroll
    for (int nt = 0; nt < NT; ++nt)
#pragma unroll
      for (int r = 0; r < 16; ++r) acc[Mt][nt][r] = bv[nt];

  for (int cc = 0; cc < nchunks; ++cc) {
    const int ccg = cc0 + cc;
    __syncthreads();
    // ---- stage input with fused BN+relu ----
    {
      float sc8[8], sh8[8];
      int ch = ccg * 32 + sg * 8;
      float4 a0 = *(const float4*)&s_coef[ch];
      float4 a1 = *(const float4*)&s_coef[ch + 4];
      float4 b0 = *(const float4*)&s_coef[C + ch];
      float4 b1 = *(const float4*)&s_coef[C + ch + 4];
      sc8[0] = a0.x; sc8[1] = a0.y; sc8[2] = a0.z; sc8[3] = a0.w;
      sc8[4] = a1.x; sc8[5] = a1.y; sc8[6] = a1.z; sc8[7] = a1.w;
      sh8[0] = b0.x; sh8[1] = b0.y; sh8[2] = b0.z; sh8[3] = b0.w;
      sh8[4] = b1.x; sh8[5] = b1.y; sh8[6] = b1.z; sh8[7] = b1.w;
#pragma unroll
      for (int it = 0; it < NIT; ++it) {
        if (ldst[it] < 0) continue;
        ushort_t v8[8] = {0, 0, 0, 0, 0, 0, 0, 0};
        if (gsrc[it] >= 0) {
          uint4 raw = *(const uint4*)&in[gsrc[it] + ccg * 32];
          const ushort_t* rp = (const ushort_t*)&raw;
#pragma unroll
          for (int j = 0; j < 8; ++j)
            v8[j] = f2bf(fmaxf(bf2f(rp[j]) * sc8[j] + sh8[j], 0.f));
        }
        *(uint4*)&s_in[ldst[it]] = *(const uint4*)v8;
      }
    }
    // ---- stage weight slice ----
    {
      const int NW = NT * 1152;
      for (int u = tid; u < NW; u += NTHREADS) {
        int l16 = u & 63, grp = u >> 6;
        int nt = grp % NT, ps = grp / NT;
        const ushort_t* src =
            w2 + ((size_t)((ccg * 18 + ps) * Ntg + z_oc * NT + nt) * 64 + l16) * 8;
        *(uint4*)&s_w[(size_t)u * 8] = *(const uint4*)src;
      }
    }
    __syncthreads();
#pragma unroll
    for (int ky = 0; ky < 3; ++ky) {
      int rowoff = (wv + ky) * (66 * 32);
#pragma unroll
      for (int kx = 0; kx < 3; ++kx) {
        const int pos = ky * 3 + kx;
#pragma unroll
        for (int s = 0; s < 2; ++s) {
          short8 Bf[NT];
#pragma unroll
          for (int nt = 0; nt < NT; ++nt)
            Bf[nt] = *(const short8*)&s_w[((pos * 2 + s) * NT + nt) * 512 + lane * 8];
#pragma unroll
          for (int Mt = 0; Mt < 2; ++Mt) {
            short8 Af = *(const short8*)&s_in[rowoff + pc[s][Mt][kx]];
#pragma unroll
            for (int nt = 0; nt < NT; ++nt)
              acc[Mt][nt] =
                  __builtin_amdgcn_mfma_f32_32x32x16_bf16(Af, Bf[nt], acc[Mt][nt], 0, 0, 0);
          }
        }
      }
    }
  }

  // ---- epilogue ----
  const int y = y0 + wv;
  const bool yok = (y < H);
  const int Ntot = Ntg * 32;

  if (HEAD) {
    if (yok) {
      float* hp = hpart + (size_t)z * (size_t)(H * W) * 32;
#pragma unroll
      for (int Mt = 0; Mt < 2; ++Mt)
#pragma unroll
        for (int r = 0; r < 16; ++r) {
          int m = (r & 3) + 8 * (r >> 2) + 4 * lh;
          int x = x0 + Mt * 32 + m;
          if (x < W) {
            size_t sp = (size_t)y * W + x;
            hp[sp * 32 + lc] = acc[Mt][0][r];  // coalesced
          }
        }
    }
    return;
  }

  if (!POOL) {
    if (yok) {
#pragma unroll
      for (int Mt = 0; Mt < 2; ++Mt)
#pragma unroll
        for (int r = 0; r < 16; ++r) {
          int m = (r & 3) + 8 * (r >> 2) + 4 * lh;
          int x = x0 + Mt * 32 + m;
          if (x < W) {
            size_t sp = (size_t)y * W + x;
#pragma unroll
            for (int nt = 0; nt < NT; ++nt) {
              int oc = (z * NT + nt) * 32 + lc;
              obf[sp * Ntot + oc] = f2bf(acc[Mt][nt][r]);
            }
          }
        }
    }
  }

  if (STATS) {
    float s1[NT], s2[NT];
#pragma unroll
    for (int nt = 0; nt < NT; ++nt) { s1[nt] = 0.f; s2[nt] = 0.f; }
    if (yok) {
#pragma unroll
      for (int Mt = 0; Mt < 2; ++Mt)
#pragma unroll
        for (int r = 0; r < 16; ++r) {
          int m = (r & 3) + 8 * (r >> 2) + 4 * lh;
          int x = x0 + Mt * 32 + m;
          if (x < W) {
#pragma unroll
            for (int nt = 0; nt < NT; ++nt) {
              float v = acc[Mt][nt][r];
              s1[nt] += v;
              s2[nt] += v * v;
            }
          }
        }
    }
#pragma unroll
    for (int nt = 0; nt < NT; ++nt) {
      s1[nt] += __shfl_xor(s1[nt], 32);
      s2[nt] += __shfl_xor(s2[nt], 32);
    }
    __syncthreads();
    float* red = (float*)s_in;
    if (lh == 0) {
#pragma unroll
      for (int nt = 0; nt < NT; ++nt) {
        red[(wv * NT + nt) * 32 + lc] = s1[nt];
        red[WAVES * NT * 32 + (wv * NT + nt) * 32 + lc] = s2[nt];
      }
    }
    __syncthreads();
    if (wv == 0 && lh == 0) {
#pragma unroll
      for (int nt = 0; nt < NT; ++nt) {
        float a = 0.f, b = 0.f;
#pragma unroll
        for (int w8 = 0; w8 < WAVES; ++w8) {
          a += red[(w8 * NT + nt) * 32 + lc];
          b += red[WAVES * NT * 32 + (w8 * NT + nt) * 32 + lc];
        }
        int ch = (z * NT + nt) * 32 + lc;
        atomicAdd(&statacc[ch], a);
        atomicAdd(&statacc[ch + 256], b);
      }
    }
  }

  if (POOL) {
    const int OWp = W >> 1, OHp = H >> 1;
    float hm[2][NT][8];
#pragma unroll
    for (int Mt = 0; Mt < 2; ++Mt)
#pragma unroll
      for (int nt = 0; nt < NT; ++nt)
#pragma unroll
        for (int i = 0; i < 8; ++i)
          hm[Mt][nt][i] = fmaxf(acc[Mt][nt][2 * i], acc[Mt][nt][2 * i + 1]);
    __syncthreads();
    float* pl = (float*)s_in;
    if (wv & 1) {
#pragma unroll
      for (int Mt = 0; Mt < 2; ++Mt)
#pragma unroll
        for (int nt = 0; nt < NT; ++nt)
#pragma unroll
          for (int i = 0; i < 8; ++i)
            pl[((((wv >> 1) * 2 + Mt) * NT + nt) * 8 + i) * 64 + lane] = hm[Mt][nt][i];
    }
    __syncthreads();
    if (!(wv & 1)) {
      int oy = (y0 + wv) >> 1;
      if (oy < OHp) {
#pragma unroll
        for (int Mt = 0; Mt < 2; ++Mt)
#pragma unroll
          for (int i = 0; i < 8; ++i) {
            int pxl = Mt * 16 + (i >> 1) * 4 + (i & 1) + 2 * lh;
            int ox = (x0 >> 1) + pxl;
            if (ox < OWp) {
#pragma unroll
              for (int nt = 0; nt < NT; ++nt) {
                float v = fmaxf(
                    hm[Mt][nt][i],
                    pl[((((wv >> 1) * 2 + Mt) * NT + nt) * 8 + i) * 64 + lane]);
                int oc = (z * NT + nt) * 32 + lc;
                obf[((size_t)oy * OWp + ox) * Ntot + oc] = f2bf(v);
              }
            }
          }
      }
    }
  }
}

// ------------------------------------------------------------------
// Head reduce: sum nz HWC(x32) fp32 partial slices -> 24 CHW planes.
// ------------------------------------------------------------------

__global__ __launch_bounds__(256) void head_reduce(const float* __restrict__ hp,
                                                   float* __restrict__ out, int HW,
                                                   int nz) {
  __shared__ float t[256 * 33];
  int tid = threadIdx.x;
  int sp0 = blockIdx.x * 256;
  int lim = (HW - sp0) * 32;
#pragma unroll 4
  for (int i = 0; i < 32; ++i) {
    int e = i * 256 + tid;
    float s = 0.f;
    if (e < lim) {
      size_t gidx = (size_t)sp0 * 32 + e;
      for (int z = 0; z < nz; ++z) s += hp[(size_t)z * HW * 32 + gidx];
    }
    t[(e >> 5) * 33 + (e & 31)] = s;
  }
  __syncthreads();
  int sp = sp0 + tid;
  if (sp < HW) {
#pragma unroll
    for (int ch = 0; ch < 24; ++ch)
      out[(size_t)ch * HW + sp] = t[tid * 33 + ch];
  }
}

// ------------------------------------------------------------------

extern "C" void kernel_launch(void* const* d_in, const int* in_sizes, int n_in,
                              void* d_out, int out_size, void* d_ws, size_t ws_size,
                              hipStream_t stream) {
  (void)in_sizes; (void)n_in; (void)out_size; (void)ws_size;
  const float* pillars = (const float*)d_in[0];
  const int* coords = (const int*)d_in[1];
  const float* lin_w = (const float*)d_in[2];
  const float* lin_b = (const float*)d_in[3];
  const float* pfn_g = (const float*)d_in[4];
  const float* pfn_b = (const float*)d_in[5];
  const float* c1_w = (const float*)d_in[6];
  const float* c1_b = (const float*)d_in[7];
  const float* bn1_g = (const float*)d_in[8];
  const float* bn1_b = (const float*)d_in[9];
  const float* c2_w = (const float*)d_in[10];
  const float* c2_b = (const float*)d_in[11];
  const float* bn2_g = (const float*)d_in[12];
  const float* bn2_b = (const float*)d_in[13];
  const float* h1_w = (const float*)d_in[14];
  const float* h1_b = (const float*)d_in[15];
  const float* hbn_g = (const float*)d_in[16];
  const float* hbn_b = (const float*)d_in[17];
  const float* hb_w = (const float*)d_in[18];
  const float* hb_b = (const float*)d_in[19];
  const float* hc_w = (const float*)d_in[20];
  const float* hc_b = (const float*)d_in[21];
  float* out = (float*)d_out;

  // ---- workspace layout (bytes) ----
  char* ws = (char*)d_ws;
  float* mom     = (float*)(ws + 0);          // 216 B
  float* pfn_ss  = (float*)(ws + 512);        // 512 B
  float* bn_acc1 = (float*)(ws + 1024);       // 2048 B
  float* bn_acc2 = (float*)(ws + 3072);       // 2048 B
  float* bn_acc3 = (float*)(ws + 5120);       // 2048 B
  ushort_t* zbuf = (ushort_t*)(ws + 10752);   // 512 B zeroed scratch page
  int* winner    = (int*)(ws + 11264);        // 1774224 B
  ushort_t* feats  = (ushort_t*)(ws + 1785600);    // 20000x64 bf16 = 2560000 B
  ushort_t* c1p    = (ushort_t*)(ws + 4345600);    // 333x333x64  raw pooled
  ushort_t* c2p    = (ushort_t*)(ws + 18539392);   // 166x166x128 raw pooled
  ushort_t* h1out  = (ushort_t*)(ws + 25593728);   // 166x166x256 raw
  ushort_t* w2c1   = (ushort_t*)(ws + 39702400);   // 73728 B
  ushort_t* w2c2   = (ushort_t*)(ws + 39776128);   // 147456 B
  ushort_t* w2h1   = (ushort_t*)(ws + 39923584);   // 589824 B
  ushort_t* w2hd   = (ushort_t*)(ws + 40513408);   // 147456 B
  float* hpart     = (float*)(ws + 40660864);      // 4x27556x32x4 = 14108672 B

  const int HW3 = 166 * 166;

  // ---- upfront zero-init ----
  hipMemsetAsync(ws, 0, 11264, stream);                 // mom..zbuf (+ bn accs)
  hipMemsetAsync(winner, 0xFF, 1774224, stream);

  // ---- fused weight prep + pillar moments ----
  fused_prep<<<490, 256, 0, stream>>>(c1_w, c2_w, h1_w, hb_w, hc_w, w2c1, w2c2,
                                      w2h1, w2hd, pillars, mom);
  pfn_finalize<<<1, 64, 0, stream>>>(mom, lin_w, lin_b, pfn_g, pfn_b, pfn_ss);

  // ---- fused PFN feats + winner scatter ----
  feats_scatter<<<5079, 256, 0, stream>>>(pillars, lin_w, lin_b, pfn_ss, feats,
                                          coords, winner);

  // ---- conv1: async gather pipeline (R3-proven), stats+pool -> c1p ----
  conv_g<2, 8><<<dim3(11, 84, 1), 512, 0, stream>>>(
      winner, feats, w2c1, c1_b, zbuf, c1p, bn_acc1, 666, 666, 2, 2);

  // ---- conv2: sync MODE1 (BN from bn_acc1 in-block), stats+pool -> c2p ----
  conv_s<2, 8, false, true, true><<<dim3(6, 42, 2), 512, 0, stream>>>(
      c1p, w2c2, c2_b, nullptr, bn_acc1, bn1_g, bn1_b, 1.f / 443556.f, c2p, nullptr,
      bn_acc2, 333, 333, 64, 2, 4);

  // ---- h1: sync MODE1 (BN from bn_acc2), oc-split z=4, stats -> h1out ----
  conv_s<2, 4, false, true, false><<<dim3(3, 42, 4), 256, 0, stream>>>(
      c2p, w2h1, h1_b, nullptr, bn_acc2, bn2_g, bn2_b, 1.f / 110889.f, h1out, nullptr,
      bn_acc3, 166, 166, 128, 4, 8);

  // ---- heads: sync MODE1 (BN from bn_acc3), K-split z=4 -> hpart partials ----
  conv_s<1, 4, true, false, false><<<dim3(3, 42, 4), 256, 0, stream>>>(
      h1out, w2hd, hb_b, hc_b, bn_acc3, hbn_g, hbn_b, 1.f / 27556.f, nullptr, hpart,
      nullptr, 166, 166, 256, 2, 1);
  head_reduce<<<(HW3 + 255) / 256, 256, 0, stream>>>(hpart, out, HW3, 4);
}

// Round 7
// 283.561 us; speedup vs baseline: 1.2516x; 1.0901x over previous
//
#include <hip/hip_runtime.h>
#include <hip/hip_bf16.h>
#include <cstdint>
#include <cstddef>

#define BN_EPS 1e-5f

typedef short short8 __attribute__((ext_vector_type(8)));
typedef float float16 __attribute__((ext_vector_type(16)));
typedef unsigned short ushort_t;

__device__ __forceinline__ float bf2f(ushort_t u) {
  return __uint_as_float(((unsigned int)u) << 16);
}
__device__ __forceinline__ ushort_t f2bf(float f) {
  unsigned int u = __float_as_uint(f);
  u += 0x7FFFu + ((u >> 16) & 1u);
  return (ushort_t)(u >> 16);
}

// async global -> LDS, 16 B per lane; dest is wave-uniform base (+lane*16 in HW)
__device__ __forceinline__ void gload16(const ushort_t* g, ushort_t* l) {
  __builtin_amdgcn_global_load_lds(
      (const __attribute__((address_space(1))) unsigned int*)g,
      (__attribute__((address_space(3))) unsigned int*)l, 16, 0, 0);
}

// ------------------------------------------------------------------
// Weight prep: OIHW fp32 -> fragment-ordered bf16 (Kc=32, 18 K16 slices)
// ------------------------------------------------------------------

__device__ __forceinline__ void prep_one(const float* __restrict__ w,
                                         ushort_t* __restrict__ w2, int C, int N,
                                         int Ntg, int chunks, int u) {
  int total = chunks * 9 * 2 * Ntg * 64;
  if (u >= total) return;
  int l = u & 63;
  int g = u >> 6;
  int ntg = g % Ntg;
  int g2 = g / Ntg;
  int s = g2 & 1;
  int g3 = g2 >> 1;
  int pos = g3 % 9;
  int cc = g3 / 9;
  int n = ntg * 32 + (l & 31);
  int c0 = cc * 32 + s * 16 + (l >> 5) * 8;
  ushort_t o8[8];
#pragma unroll
  for (int j = 0; j < 8; ++j) {
    int c = c0 + j;
    float v = (n < N && c < C) ? w[((size_t)n * C + c) * 9 + pos] : 0.f;
    o8[j] = f2bf(v);
  }
  *(uint4*)&w2[(size_t)u * 8] = *(const uint4*)o8;
}

__device__ __forceinline__ void prep_head_one(const float* __restrict__ hb,
                                              const float* __restrict__ hc,
                                              ushort_t* __restrict__ w2, int u) {
  int total = 8 * 9 * 2 * 64;
  if (u >= total) return;
  int l = u & 63;
  int g = u >> 6;
  int s = g & 1;
  int g3 = g >> 1;
  int pos = g3 % 9;
  int cc = g3 / 9;
  int n = l & 31;
  int c0 = cc * 32 + s * 16 + (l >> 5) * 8;
  ushort_t o8[8];
#pragma unroll
  for (int j = 0; j < 8; ++j) {
    int c = c0 + j;
    float v = 0.f;
    if (n < 21) v = hb[((size_t)n * 256 + c) * 9 + pos];
    else if (n < 24) v = hc[((size_t)(n - 21) * 256 + c) * 9 + pos];
    o8[j] = f2bf(v);
  }
  *(uint4*)&w2[(size_t)u * 8] = *(const uint4*)o8;
}

// ------------------------------------------------------------------
// fused_prep: [0,234) weight prep; [234,490) pillar moments;
// [490,599) winner-map fill (-1) -- deletes a memset dispatch.
// ------------------------------------------------------------------

__global__ __launch_bounds__(256) void fused_prep(
    const float* __restrict__ c1_w, const float* __restrict__ c2_w,
    const float* __restrict__ h1_w, const float* __restrict__ hb_w,
    const float* __restrict__ hc_w, ushort_t* __restrict__ w2c1,
    ushort_t* __restrict__ w2c2, ushort_t* __restrict__ w2h1,
    ushort_t* __restrict__ w2hd, const float* __restrict__ pillars,
    float* __restrict__ mom, int* __restrict__ winner) {
  int b = blockIdx.x;
  int t = threadIdx.x;
  if (b < 18) { prep_one(c1_w, w2c1, 64, 64, 2, 2, b * 256 + t); return; }
  if (b < 54) { prep_one(c2_w, w2c2, 64, 128, 4, 2, (b - 18) * 256 + t); return; }
  if (b < 198) { prep_one(h1_w, w2h1, 128, 256, 8, 4, (b - 54) * 256 + t); return; }
  if (b < 234) { prep_head_one(hb_w, hc_w, w2hd, (b - 198) * 256 + t); return; }
  if (b >= 490) {
    // winner fill: 666*666 ints = 110889 int4s, -1 everywhere
    int gid = (b - 490) * 256 + t;
#pragma unroll
    for (int k = 0; k < 4; ++k) {
      int i4 = gid + k * 27904;
      if (i4 < 110889) {
        int4 v = make_int4(-1, -1, -1, -1);
        ((int4*)winner)[i4] = v;
      }
    }
    return;
  }
  // ---- pillar moments: S[9], M[45] upper-tri, 256 blocks x 256 thr ----
  float S[9], M[45];
#pragma unroll
  for (int i = 0; i < 9; ++i) S[i] = 0.f;
#pragma unroll
  for (int i = 0; i < 45; ++i) M[i] = 0.f;
  const int t0 = (b - 234) * 256 + t;
  const int NTH = 256 * 256;
  for (long r = t0; r < 640000; r += NTH) {
    float x[9];
    const float* rp = pillars + r * 9;
#pragma unroll
    for (int d = 0; d < 9; ++d) x[d] = rp[d];
    int k = 0;
#pragma unroll
    for (int i = 0; i < 9; ++i) {
      S[i] += x[i];
#pragma unroll
      for (int j = i; j < 9; ++j) { M[k] += x[i] * x[j]; ++k; }
    }
  }
#pragma unroll
  for (int i = 0; i < 9; ++i)
#pragma unroll
    for (int o = 32; o > 0; o >>= 1) S[i] += __shfl_xor(S[i], o);
#pragma unroll
  for (int i = 0; i < 45; ++i)
#pragma unroll
    for (int o = 32; o > 0; o >>= 1) M[i] += __shfl_xor(M[i], o);
  __shared__ float red[4 * 54];
  int lane = t & 63, wv = t >> 6;
  if (lane == 0) {
#pragma unroll
    for (int i = 0; i < 9; ++i) red[wv * 54 + i] = S[i];
#pragma unroll
    for (int i = 0; i < 45; ++i) red[wv * 54 + 9 + i] = M[i];
  }
  __syncthreads();
  if (t < 54) {
    float s = 0.f;
#pragma unroll
    for (int w4 = 0; w4 < 4; ++w4) s += red[w4 * 54 + t];
    atomicAdd(&mom[t], s);
  }
}

// ------------------------------------------------------------------
// pfn_finalize: 64 threads; double-precision algebra moments -> scale/shift
// ------------------------------------------------------------------

__global__ void pfn_finalize(const float* __restrict__ mom,
                             const float* __restrict__ lin_w,
                             const float* __restrict__ lin_b,
                             const float* __restrict__ g, const float* __restrict__ b,
                             float* __restrict__ ss) {
  int c = threadIdx.x;
  double w[9], S[9];
#pragma unroll
  for (int d = 0; d < 9; ++d) {
    w[d] = (double)lin_w[c * 9 + d];
    S[d] = (double)mom[d];
  }
  double wS = 0.0;
#pragma unroll
  for (int d = 0; d < 9; ++d) wS += w[d] * S[d];
  double wMw = 0.0;
  int k = 0;
#pragma unroll
  for (int i = 0; i < 9; ++i)
#pragma unroll
    for (int j = i; j < 9; ++j) {
      double m = (double)mom[9 + k];
      wMw += (i == j ? 1.0 : 2.0) * w[i] * w[j] * m;
      ++k;
    }
  const double N = 640000.0;
  double bc = (double)lin_b[c];
  double mean = (wS + N * bc) / N;
  double ey2 = (wMw + 2.0 * bc * wS + N * bc * bc) / N;
  double var = ey2 - mean * mean;
  if (var < 0.0) var = 0.0;
  double inv = 1.0 / sqrt(var + (double)BN_EPS);
  double sc = (double)g[c] * inv;
  ss[c] = (float)sc;
  ss[c + 64] = (float)((double)b[c] - mean * sc);
}

// ------------------------------------------------------------------
// feats_scatter: blocks [0,5000) PFN feats; [5000,5079) winner scatter.
// ------------------------------------------------------------------

__global__ __launch_bounds__(256) void feats_scatter(
    const float* __restrict__ pillars, const float* __restrict__ lin_w,
    const float* __restrict__ lin_b, const float* __restrict__ ss,
    ushort_t* __restrict__ feats, const int* __restrict__ coords,
    int* __restrict__ winner) {
  int tid = threadIdx.x;
  if (blockIdx.x < 5000) {
    __shared__ float s_p[1152];
    int c = tid & 63, pe = tid >> 6;
    long pb = (long)blockIdx.x * 4;
    for (int i = tid; i < 1152; i += 256) s_p[i] = pillars[pb * 288 + i];
    float w[9];
#pragma unroll
    for (int d = 0; d < 9; ++d) w[d] = lin_w[c * 9 + d];
    float bl = lin_b[c];
    float sc = ss[c], sh = ss[c + 64];
    __syncthreads();
    const float* pp = &s_p[pe * 288];
    float m = -1e30f;
#pragma unroll 4
    for (int n = 0; n < 32; ++n) {
      float y = bl;
#pragma unroll
      for (int d = 0; d < 9; ++d) y += pp[n * 9 + d] * w[d];
      float v = fmaxf(y * sc + sh, 0.f);
      m = fmaxf(m, v);
    }
    feats[(pb + pe) * 64 + c] = f2bf(m);
  } else {
    int p = (blockIdx.x - 5000) * 256 + tid;
    if (p >= 20000) return;
    int y = coords[p * 3 + 1], x = coords[p * 3 + 2];
    if (y >= 0 && y < 666 && x >= 0 && x < 666) atomicMax(&winner[y * 666 + x], p);
  }
}

// ------------------------------------------------------------------
// conv_g: conv1 only. Async gather conv (R3-proven): winner->feats
// indirection, all staging via global_load_lds, K=16 phases double-
// buffered. Fused BN stats + raw 2x2 max-pool.
// ------------------------------------------------------------------

template <int NT, int WAVES>
__global__ __launch_bounds__(WAVES * 64, 4) void conv_g(
    const int* __restrict__ winner, const ushort_t* __restrict__ feats,
    const ushort_t* __restrict__ w2, const float* __restrict__ bias,
    const ushort_t* __restrict__ zbuf, ushort_t* __restrict__ obf,
    float* __restrict__ statacc, int W, int H, int nchunks, int Ntg) {
  constexpr int NTHREADS = WAVES * 64;
  constexpr int NPOS = (WAVES + 2) * 66;
  constexpr int IN_U4 = NPOS * 2;
  constexpr int W_U4 = 9 * NT * 64;
  constexpr int INIT = (IN_U4 + NTHREADS - 1) / NTHREADS;
  constexpr int WIT = (W_U4 + NTHREADS - 1) / NTHREADS;
  constexpr int IN_SLOTS = ((IN_U4 + 63) / 64) * 64;
  __shared__ ushort_t s_in[2][IN_SLOTS * 8];
  __shared__ ushort_t s_w[2][W_U4 * 8];
  const int tid = threadIdx.x;
  const int lane = tid & 63, wv = tid >> 6;
  const int lc = lane & 31, lh = lane >> 5;
  const int x0 = blockIdx.x * 64, y0 = blockIdx.y * WAVES;
  const int z = blockIdx.z;
  const int z_oc = z;

  int pc[2][3];
#pragma unroll
  for (int Mt = 0; Mt < 2; ++Mt)
#pragma unroll
    for (int kx = 0; kx < 3; ++kx) {
      int col = Mt * 32 + kx + lc;
      pc[Mt][kx] = col * 16 + (lh ^ (col & 1)) * 8;
    }

  const ushort_t* isrc[INIT];
#pragma unroll
  for (int it = 0; it < INIT; ++it) {
    isrc[it] = zbuf;
    int d = it * NTHREADS + tid;
    if (d < IN_U4) {
      int p = d >> 1, g = d & 1;
      int r = p / 66, col = p - r * 66;
      int cg = g ^ (col & 1);
      int gy = y0 - 1 + r, gx = x0 - 1 + col;
      if (gy >= 0 && gy < H && gx >= 0 && gx < W) {
        int pw = winner[gy * 666 + gx];
        if (pw >= 0) isrc[it] = feats + pw * 64 + cg * 8;
      }
    }
  }
  int wof[WIT];
#pragma unroll
  for (int it = 0; it < WIT; ++it) {
    wof[it] = 0;
    int d = it * NTHREADS + tid;
    if (d < W_U4) {
      int grp = d >> 6, l16 = d & 63;
      int pos = grp / NT, nt = grp % NT;
      wof[it] = (pos * 2 * Ntg + z_oc * NT + nt) * 512 + l16 * 8;
    }
  }

  float bv[NT];
#pragma unroll
  for (int nt = 0; nt < NT; ++nt) bv[nt] = bias[(z * NT + nt) * 32 + lc];
  float16 acc[2][NT];
#pragma unroll
  for (int Mt = 0; Mt < 2; ++Mt)
#pragma unroll
    for (int nt = 0; nt < NT; ++nt)
#pragma unroll
      for (int r = 0; r < 16; ++r) acc[Mt][nt][r] = bv[nt];

  auto stage = [&](int ph, int b) {
    int ccg = ph >> 1, sh2 = ph & 1;
    int coff = ccg * 32 + sh2 * 16;
#pragma unroll
    for (int it = 0; it < INIT; ++it) {
      int d = it * NTHREADS + tid;
      if (d < IN_U4)
        gload16(isrc[it] + coff, &s_in[b][(size_t)(it * NTHREADS + wv * 64) * 8]);
    }
    int wbase = (ccg * 18 + sh2) * Ntg * 512;
#pragma unroll
    for (int it = 0; it < WIT; ++it) {
      int d = it * NTHREADS + tid;
      if (d < W_U4)
        gload16(w2 + wbase + wof[it], &s_w[b][(size_t)(it * NTHREADS + wv * 64) * 8]);
    }
  };

  auto compute_phase = [&](int b) {
#pragma unroll
    for (int ky = 0; ky < 3; ++ky) {
      const ushort_t* rowp = &s_in[b][(wv + ky) * (66 * 16)];
#pragma unroll
      for (int kx = 0; kx < 3; ++kx) {
        const int pos = ky * 3 + kx;
        short8 Bf[NT];
#pragma unroll
        for (int nt = 0; nt < NT; ++nt)
          Bf[nt] = *(const short8*)&s_w[b][(pos * NT + nt) * 512 + lane * 8];
#pragma unroll
        for (int Mt = 0; Mt < 2; ++Mt) {
          short8 Af = *(const short8*)&rowp[pc[Mt][kx]];
#pragma unroll
          for (int nt = 0; nt < NT; ++nt)
            acc[Mt][nt] =
                __builtin_amdgcn_mfma_f32_32x32x16_bf16(Af, Bf[nt], acc[Mt][nt], 0, 0, 0);
        }
      }
    }
  };

  const int nph = nchunks * 2;
  stage(0, 0);
  for (int ph = 0; ph < nph; ++ph) {
    asm volatile("s_waitcnt vmcnt(0)\n\ts_barrier" ::: "memory");
    if (ph + 1 < nph) stage(ph + 1, (ph + 1) & 1);
    __builtin_amdgcn_s_setprio(1);
    compute_phase(ph & 1);
    __builtin_amdgcn_s_setprio(0);
  }

  // ---- epilogue: fused BN stats + 2x2 max-pool store ----
  const int y = y0 + wv;
  const bool yok = (y < H);
  const int Ntot = Ntg * 32;

  {
    float s1[NT], s2[NT];
#pragma unroll
    for (int nt = 0; nt < NT; ++nt) { s1[nt] = 0.f; s2[nt] = 0.f; }
    if (yok) {
#pragma unroll
      for (int Mt = 0; Mt < 2; ++Mt)
#pragma unroll
        for (int r = 0; r < 16; ++r) {
          int m = (r & 3) + 8 * (r >> 2) + 4 * lh;
          int x = x0 + Mt * 32 + m;
          if (x < W) {
#pragma unroll
            for (int nt = 0; nt < NT; ++nt) {
              float v = acc[Mt][nt][r];
              s1[nt] += v;
              s2[nt] += v * v;
            }
          }
        }
    }
#pragma unroll
    for (int nt = 0; nt < NT; ++nt) {
      s1[nt] += __shfl_xor(s1[nt], 32);
      s2[nt] += __shfl_xor(s2[nt], 32);
    }
    __syncthreads();
    float* red = (float*)s_in;
    if (lh == 0) {
#pragma unroll
      for (int nt = 0; nt < NT; ++nt) {
        red[(wv * NT + nt) * 32 + lc] = s1[nt];
        red[WAVES * NT * 32 + (wv * NT + nt) * 32 + lc] = s2[nt];
      }
    }
    __syncthreads();
    if (wv == 0 && lh == 0) {
#pragma unroll
      for (int nt = 0; nt < NT; ++nt) {
        float a = 0.f, b = 0.f;
#pragma unroll
        for (int w8 = 0; w8 < WAVES; ++w8) {
          a += red[(w8 * NT + nt) * 32 + lc];
          b += red[WAVES * NT * 32 + (w8 * NT + nt) * 32 + lc];
        }
        int ch = (z * NT + nt) * 32 + lc;
        atomicAdd(&statacc[ch], a);
        atomicAdd(&statacc[ch + 256], b);
      }
    }
  }

  {
    const int OWp = W >> 1, OHp = H >> 1;
    float hm[2][NT][8];
#pragma unroll
    for (int Mt = 0; Mt < 2; ++Mt)
#pragma unroll
      for (int nt = 0; nt < NT; ++nt)
#pragma unroll
        for (int i = 0; i < 8; ++i)
          hm[Mt][nt][i] = fmaxf(acc[Mt][nt][2 * i], acc[Mt][nt][2 * i + 1]);
    __syncthreads();
    float* pl = (float*)s_in;
    if (wv & 1) {
#pragma unroll
      for (int Mt = 0; Mt < 2; ++Mt)
#pragma unroll
        for (int nt = 0; nt < NT; ++nt)
#pragma unroll
          for (int i = 0; i < 8; ++i)
            pl[((((wv >> 1) * 2 + Mt) * NT + nt) * 8 + i) * 64 + lane] = hm[Mt][nt][i];
    }
    __syncthreads();
    if (!(wv & 1)) {
      int oy = (y0 + wv) >> 1;
      if (oy < OHp) {
#pragma unroll
        for (int Mt = 0; Mt < 2; ++Mt)
#pragma unroll
          for (int i = 0; i < 8; ++i) {
            int pxl = Mt * 16 + (i >> 1) * 4 + (i & 1) + 2 * lh;
            int ox = (x0 >> 1) + pxl;
            if (ox < OWp) {
#pragma unroll
              for (int nt = 0; nt < NT; ++nt) {
                float v = fmaxf(
                    hm[Mt][nt][i],
                    pl[((((wv >> 1) * 2 + Mt) * NT + nt) * 8 + i) * 64 + lane]);
                int oc = (z * NT + nt) * 32 + lc;
                obf[((size_t)oy * OWp + ox) * Ntot + oc] = f2bf(v);
              }
            }
          }
      }
    }
  }
}

// ------------------------------------------------------------------
// conv_s: sync MODE-1 conv: BN+relu fused at staging from raw bf16 HWC;
// BN coefs computed IN-BLOCK from stat accumulators. MT = output tile
// width in 32-col units (2 = 64-wide, 1 = 32-wide).
// HEAD (MT=1, z=1, nchunks=8): NO K-split -- full K=256 in one block,
// direct fp32 CHW store via LDS transpose (no hpart, no reduce, no
// atomics; R5 showed CHW-scattered atomics are 2.5x poison).
// STATS: fused BN stats. POOL: fused raw 2x2 max-pool.
// ------------------------------------------------------------------

template <int NT, int MT, int WAVES, bool HEAD, bool STATS, bool POOL>
__global__ __launch_bounds__(WAVES * 64, MT == 1 ? 4 : (WAVES == 8 ? 4 : 3)) void conv_s(
    const ushort_t* __restrict__ in, const ushort_t* __restrict__ w2,
    const float* __restrict__ bias, const float* __restrict__ bias2,
    const float* __restrict__ bnacc, const float* __restrict__ bng,
    const float* __restrict__ bnb, float invN, ushort_t* __restrict__ obf,
    float* __restrict__ hout, float* __restrict__ statacc, int W, int H, int C,
    int nchunks, int Ntg) {
  constexpr int NTHREADS = WAVES * 64;
  constexpr int XCOLS = MT * 32 + 2;
  __shared__ ushort_t s_in[(WAVES + 2) * XCOLS * 32];
  __shared__ ushort_t s_w[9 * 2 * NT * 512];
  __shared__ float s_coef[512];
  const int tid = threadIdx.x;
  const int lane = tid & 63, wv = tid >> 6;
  const int lc = lane & 31, lh = lane >> 5;
  const int x0 = blockIdx.x * (MT * 32), y0 = blockIdx.y * WAVES;
  const int z = blockIdx.z;
  const int z_oc = HEAD ? 0 : z;

  // in-block BN coef compute (covered by first loop-top __syncthreads)
  if (tid < C) {
    float m = bnacc[tid] * invN;
    float v = fmaxf(bnacc[tid + 256] * invN - m * m, 0.f);
    float sc = bng[tid] * rsqrtf(v + BN_EPS);
    s_coef[tid] = sc;
    s_coef[C + tid] = bnb[tid] - m * sc;
  }

  // per-lane A-address precompute
  int pc[2][2][3];
#pragma unroll
  for (int s = 0; s < 2; ++s)
#pragma unroll
    for (int Mt = 0; Mt < MT; ++Mt)
#pragma unroll
      for (int kx = 0; kx < 3; ++kx) {
        int col = Mt * 32 + kx + lc;
        int q = (2 * s + lh) ^ ((col >> 1) & 3);
        pc[s][Mt][kx] = col * 32 + q * 8;
      }

  // hoisted staging descriptors
  const int sg = tid & 3;
  const int tpos = tid >> 2;
  constexpr int TPOS = NTHREADS / 4;
  constexpr int NPOS = (WAVES + 2) * XCOLS;
  constexpr int NIT = (NPOS + TPOS - 1) / TPOS;
  int ldst[NIT], gsrc[NIT];
#pragma unroll
  for (int it = 0; it < NIT; ++it) {
    ldst[it] = -1;
    gsrc[it] = -1;
    int p = tpos + it * TPOS;
    if (p < NPOS) {
      int r = p / XCOLS, col = p - r * XCOLS;
      int f = sg ^ ((col >> 1) & 3);
      ldst[it] = (r * XCOLS + col) * 32 + f * 8;
      int gy = y0 - 1 + r, gx = x0 - 1 + col;
      if (gy >= 0 && gy < H && gx >= 0 && gx < W)
        gsrc[it] = (gy * W + gx) * C + sg * 8;
    }
  }

  float bv[NT];
#pragma unroll
  for (int nt = 0; nt < NT; ++nt) {
    if (HEAD) {
      bv[nt] = lc < 21 ? bias[lc] : (lc < 24 ? bias2[lc - 21] : 0.f);
    } else {
      bv[nt] = bias[(z * NT + nt) * 32 + lc];
    }
  }
  float16 acc[2][NT];
#pragma unroll
  for (int Mt = 0; Mt < MT; ++Mt)
#pragma unroll
    for (int nt = 0; nt < NT; ++nt)
#pragma unroll
      for (int r = 0; r < 16; ++r) acc[Mt][nt][r] = bv[nt];

  for (int cc = 0; cc < nchunks; ++cc) {
    const int ccg = cc;
    __syncthreads();
    // ---- stage input with fused BN+relu ----
    {
      float sc8[8], sh8[8];
      int ch = ccg * 32 + sg * 8;
      float4 a0 = *(const float4*)&s_coef[ch];
      float4 a1 = *(const float4*)&s_coef[ch + 4];
      float4 b0 = *(const float4*)&s_coef[C + ch];
      float4 b1 = *(const float4*)&s_coef[C + ch + 4];
      sc8[0] = a0.x; sc8[1] = a0.y; sc8[2] = a0.z; sc8[3] = a0.w;
      sc8[4] = a1.x; sc8[5] = a1.y; sc8[6] = a1.z; sc8[7] = a1.w;
      sh8[0] = b0.x; sh8[1] = b0.y; sh8[2] = b0.z; sh8[3] = b0.w;
      sh8[4] = b1.x; sh8[5] = b1.y; sh8[6] = b1.z; sh8[7] = b1.w;
#pragma unroll
      for (int it = 0; it < NIT; ++it) {
        if (ldst[it] < 0) continue;
        ushort_t v8[8] = {0, 0, 0, 0, 0, 0, 0, 0};
        if (gsrc[it] >= 0) {
          uint4 raw = *(const uint4*)&in[gsrc[it] + ccg * 32];
          const ushort_t* rp = (const ushort_t*)&raw;
#pragma unroll
          for (int j = 0; j < 8; ++j)
            v8[j] = f2bf(fmaxf(bf2f(rp[j]) * sc8[j] + sh8[j], 0.f));
        }
        *(uint4*)&s_in[ldst[it]] = *(const uint4*)v8;
      }
    }
    // ---- stage weight slice ----
    {
      const int NW = NT * 1152;
      for (int u = tid; u < NW; u += NTHREADS) {
        int l16 = u & 63, grp = u >> 6;
        int nt = grp % NT, ps = grp / NT;
        const ushort_t* src =
            w2 + ((size_t)((ccg * 18 + ps) * Ntg + z_oc * NT + nt) * 64 + l16) * 8;
        *(uint4*)&s_w[(size_t)u * 8] = *(const uint4*)src;
      }
    }
    __syncthreads();
#pragma unroll
    for (int ky = 0; ky < 3; ++ky) {
      int rowoff = (wv + ky) * (XCOLS * 32);
#pragma unroll
      for (int kx = 0; kx < 3; ++kx) {
        const int pos = ky * 3 + kx;
#pragma unroll
        for (int s = 0; s < 2; ++s) {
          short8 Bf[NT];
#pragma unroll
          for (int nt = 0; nt < NT; ++nt)
            Bf[nt] = *(const short8*)&s_w[((pos * 2 + s) * NT + nt) * 512 + lane * 8];
#pragma unroll
          for (int Mt = 0; Mt < MT; ++Mt) {
            short8 Af = *(const short8*)&s_in[rowoff + pc[s][Mt][kx]];
#pragma unroll
            for (int nt = 0; nt < NT; ++nt)
              acc[Mt][nt] =
                  __builtin_amdgcn_mfma_f32_32x32x16_bf16(Af, Bf[nt], acc[Mt][nt], 0, 0, 0);
          }
        }
      }
    }
  }

  // ---- epilogue ----
  const int y = y0 + wv;
  const bool yok = (y < H);
  const int Ntot = Ntg * 32;
  const int HW = H * W;

  if (HEAD) {
    // LDS transpose -> coalesced CHW stores (sole writer, full K done)
    __syncthreads();
    float* tr = (float*)s_in;  // [WAVES rows][32 x][25 ch-pad]
    if (lc < 24) {
#pragma unroll
      for (int r = 0; r < 16; ++r) {
        int m = (r & 3) + 8 * (r >> 2) + 4 * lh;
        tr[(wv * 32 + m) * 25 + lc] = acc[0][0][r];
      }
    }
    __syncthreads();
    // 24 ch x WAVES rows x 32 x  = 3072 elems; 256 thr -> 12 iters
    for (int it = 0; it < 12; ++it) {
      int idx = it * 256 + tid;
      int ch = idx >> 7;            // /128
      int rem = idx & 127;
      int yy = rem >> 5, xl = rem & 31;
      int gy = y0 + yy, gx = x0 + xl;
      if (gy < H && gx < W)
        hout[(size_t)ch * HW + (size_t)gy * W + gx] = tr[(yy * 32 + xl) * 25 + ch];
    }
    return;
  }

  if (!POOL) {
    if (yok) {
#pragma unroll
      for (int Mt = 0; Mt < MT; ++Mt)
#pragma unroll
        for (int r = 0; r < 16; ++r) {
          int m = (r & 3) + 8 * (r >> 2) + 4 * lh;
          int x = x0 + Mt * 32 + m;
          if (x < W) {
            size_t sp = (size_t)y * W + x;
#pragma unroll
            for (int nt = 0; nt < NT; ++nt) {
              int oc = (z * NT + nt) * 32 + lc;
              obf[sp * Ntot + oc] = f2bf(acc[Mt][nt][r]);
            }
          }
        }
    }
  }

  if (STATS) {
    float s1[NT], s2[NT];
#pragma unroll
    for (int nt = 0; nt < NT; ++nt) { s1[nt] = 0.f; s2[nt] = 0.f; }
    if (yok) {
#pragma unroll
      for (int Mt = 0; Mt < MT; ++Mt)
#pragma unroll
        for (int r = 0; r < 16; ++r) {
          int m = (r & 3) + 8 * (r >> 2) + 4 * lh;
          int x = x0 + Mt * 32 + m;
          if (x < W) {
#pragma unroll
            for (int nt = 0; nt < NT; ++nt) {
              float v = acc[Mt][nt][r];
              s1[nt] += v;
              s2[nt] += v * v;
            }
          }
        }
    }
#pragma unroll
    for (int nt = 0; nt < NT; ++nt) {
      s1[nt] += __shfl_xor(s1[nt], 32);
      s2[nt] += __shfl_xor(s2[nt], 32);
    }
    __syncthreads();
    float* red = (float*)s_in;
    if (lh == 0) {
#pragma unroll
      for (int nt = 0; nt < NT; ++nt) {
        red[(wv * NT + nt) * 32 + lc] = s1[nt];
        red[WAVES * NT * 32 + (wv * NT + nt) * 32 + lc] = s2[nt];
      }
    }
    __syncthreads();
    if (wv == 0 && lh == 0) {
#pragma unroll
      for (int nt = 0; nt < NT; ++nt) {
        float a = 0.f, b = 0.f;
#pragma unroll
        for (int w8 = 0; w8 < WAVES; ++w8) {
          a += red[(w8 * NT + nt) * 32 + lc];
          b += red[WAVES * NT * 32 + (w8 * NT + nt) * 32 + lc];
        }
        int ch = (z * NT + nt) * 32 + lc;
        atomicAdd(&statacc[ch], a);
        atomicAdd(&statacc[ch + 256], b);
      }
    }
  }

  if (POOL) {
    const int OWp = W >> 1, OHp = H >> 1;
    float hm[2][NT][8];
#pragma unroll
    for (int Mt = 0; Mt < MT; ++Mt)
#pragma unroll
      for (int nt = 0; nt < NT; ++nt)
#pragma unroll
        for (int i = 0; i < 8; ++i)
          hm[Mt][nt][i] = fmaxf(acc[Mt][nt][2 * i], acc[Mt][nt][2 * i + 1]);
    __syncthreads();
    float* pl = (float*)s_in;
    if (wv & 1) {
#pragma unroll
      for (int Mt = 0; Mt < MT; ++Mt)
#pragma unroll
        for (int nt = 0; nt < NT; ++nt)
#pragma unroll
          for (int i = 0; i < 8; ++i)
            pl[((((wv >> 1) * 2 + Mt) * NT + nt) * 8 + i) * 64 + lane] = hm[Mt][nt][i];
    }
    __syncthreads();
    if (!(wv & 1)) {
      int oy = (y0 + wv) >> 1;
      if (oy < OHp) {
#pragma unroll
        for (int Mt = 0; Mt < MT; ++Mt)
#pragma unroll
          for (int i = 0; i < 8; ++i) {
            int pxl = Mt * 16 + (i >> 1) * 4 + (i & 1) + 2 * lh;
            int ox = (x0 >> 1) + pxl;
            if (ox < OWp) {
#pragma unroll
              for (int nt = 0; nt < NT; ++nt) {
                float v = fmaxf(
                    hm[Mt][nt][i],
                    pl[((((wv >> 1) * 2 + Mt) * NT + nt) * 8 + i) * 64 + lane]);
                int oc = (z * NT + nt) * 32 + lc;
                obf[((size_t)oy * OWp + ox) * Ntot + oc] = f2bf(v);
              }
            }
          }
      }
    }
  }
}

// ------------------------------------------------------------------

extern "C" void kernel_launch(void* const* d_in, const int* in_sizes, int n_in,
                              void* d_out, int out_size, void* d_ws, size_t ws_size,
                              hipStream_t stream) {
  (void)in_sizes; (void)n_in; (void)out_size; (void)ws_size;
  const float* pillars = (const float*)d_in[0];
  const int* coords = (const int*)d_in[1];
  const float* lin_w = (const float*)d_in[2];
  const float* lin_b = (const float*)d_in[3];
  const float* pfn_g = (const float*)d_in[4];
  const float* pfn_b = (const float*)d_in[5];
  const float* c1_w = (const float*)d_in[6];
  const float* c1_b = (const float*)d_in[7];
  const float* bn1_g = (const float*)d_in[8];
  const float* bn1_b = (const float*)d_in[9];
  const float* c2_w = (const float*)d_in[10];
  const float* c2_b = (const float*)d_in[11];
  const float* bn2_g = (const float*)d_in[12];
  const float* bn2_b = (const float*)d_in[13];
  const float* h1_w = (const float*)d_in[14];
  const float* h1_b = (const float*)d_in[15];
  const float* hbn_g = (const float*)d_in[16];
  const float* hbn_b = (const float*)d_in[17];
  const float* hb_w = (const float*)d_in[18];
  const float* hb_b = (const float*)d_in[19];
  const float* hc_w = (const float*)d_in[20];
  const float* hc_b = (const float*)d_in[21];
  float* out = (float*)d_out;

  // ---- workspace layout (bytes) ----
  char* ws = (char*)d_ws;
  float* mom     = (float*)(ws + 0);          // 216 B
  float* pfn_ss  = (float*)(ws + 512);        // 512 B
  float* bn_acc1 = (float*)(ws + 1024);       // 2048 B
  float* bn_acc2 = (float*)(ws + 3072);       // 2048 B
  float* bn_acc3 = (float*)(ws + 5120);       // 2048 B
  ushort_t* zbuf = (ushort_t*)(ws + 10752);   // 512 B zeroed scratch page
  int* winner    = (int*)(ws + 11264);        // 1774224 B
  ushort_t* feats  = (ushort_t*)(ws + 1785600);    // 20000x64 bf16 = 2560000 B
  ushort_t* c1p    = (ushort_t*)(ws + 4345600);    // 333x333x64  raw pooled
  ushort_t* c2p    = (ushort_t*)(ws + 18539392);   // 166x166x128 raw pooled
  ushort_t* h1out  = (ushort_t*)(ws + 25593728);   // 166x166x256 raw
  ushort_t* w2c1   = (ushort_t*)(ws + 39702400);   // 73728 B
  ushort_t* w2c2   = (ushort_t*)(ws + 39776128);   // 147456 B
  ushort_t* w2h1   = (ushort_t*)(ws + 39923584);   // 589824 B
  ushort_t* w2hd   = (ushort_t*)(ws + 40513408);   // 147456 B

  // ---- upfront zero-init (mom..zbuf; winner filled by fused_prep) ----
  hipMemsetAsync(ws, 0, 11264, stream);

  // ---- fused weight prep + pillar moments + winner fill ----
  fused_prep<<<599, 256, 0, stream>>>(c1_w, c2_w, h1_w, hb_w, hc_w, w2c1, w2c2,
                                      w2h1, w2hd, pillars, mom, winner);
  pfn_finalize<<<1, 64, 0, stream>>>(mom, lin_w, lin_b, pfn_g, pfn_b, pfn_ss);

  // ---- fused PFN feats + winner scatter ----
  feats_scatter<<<5079, 256, 0, stream>>>(pillars, lin_w, lin_b, pfn_ss, feats,
                                          coords, winner);

  // ---- conv1: async gather pipeline (R3-proven), stats+pool -> c1p ----
  conv_g<2, 8><<<dim3(11, 84, 1), 512, 0, stream>>>(
      winner, feats, w2c1, c1_b, zbuf, c1p, bn_acc1, 666, 666, 2, 2);

  // ---- conv2: sync MODE1 (BN from bn_acc1 in-block), stats+pool -> c2p ----
  conv_s<2, 2, 8, false, true, true><<<dim3(6, 42, 2), 512, 0, stream>>>(
      c1p, w2c2, c2_b, nullptr, bn_acc1, bn1_g, bn1_b, 1.f / 443556.f, c2p, nullptr,
      bn_acc2, 333, 333, 64, 2, 4);

  // ---- h1: sync MODE1 (BN from bn_acc2), oc-split z=4, stats -> h1out ----
  conv_s<2, 2, 4, false, true, false><<<dim3(3, 42, 4), 256, 0, stream>>>(
      c2p, w2h1, h1_b, nullptr, bn_acc2, bn2_g, bn2_b, 1.f / 110889.f, h1out, nullptr,
      bn_acc3, 166, 166, 128, 4, 8);

  // ---- heads: sync MODE1 (BN from bn_acc3), NO K-split, MT=1 tile,
  //      full K=256 per block, direct coalesced CHW store -> out ----
  conv_s<1, 1, 4, true, false, false><<<dim3(6, 42, 1), 256, 0, stream>>>(
      h1out, w2hd, hb_b, hc_b, bn_acc3, hbn_g, hbn_b, 1.f / 27556.f, nullptr, out,
      nullptr, 166, 166, 256, 8, 1);
}